// Round 6
// baseline (443.001 us; speedup 1.0000x reference)
//
#include <hip/hip_runtime.h>

#define SEQ   2048
#define DM    768
#define ST    100
#define KF    24
#define NC    32      // SEQ / 64
#define KJ    128     // padded state dim (inter-GEMM K, E cols, G cols)
#define NJ    112     // padded state dim (hloc-GEMM N)
#define GK2   1536    // 2 * DM  (bf16x2 split K for input GEMM)
#define KS2   8
#define KC2   192     // GK2 / KS2

using short8  = __attribute__((ext_vector_type(8))) short;
using float4v = __attribute__((ext_vector_type(4))) float;

__device__ __forceinline__ unsigned short bf16_rn(float x) {
    unsigned int u = __float_as_uint(x);
    unsigned int r = u + 0x7FFFu + ((u >> 16) & 1u);
    return (unsigned short)(r >> 16);
}
__device__ __forceinline__ float bf2f(unsigned short h) {
    return __uint_as_float(((unsigned int)h) << 16);
}
__device__ __forceinline__ void async16(const void* g, void* l) {
    __builtin_amdgcn_global_load_lds(
        (const __attribute__((address_space(1))) unsigned int*)g,
        (__attribute__((address_space(3))) unsigned int*)l, 16, 0, 0);
}
__device__ __forceinline__ void atomAddF(float* p, float v) {
#if __has_builtin(__builtin_amdgcn_global_atomic_fadd_f32)
    __builtin_amdgcn_global_atomic_fadd_f32(
        (__attribute__((address_space(1))) float*)p, v);
#else
    unsafeAtomicAdd(p, v);
#endif
}

// ---------------------------------------------------------------------------
// prep (everything independent of ut, one dispatch):
//  [0,144)      Mbig[d][k] = [Mh^T | Ml^T]           (bf16x2 split of M_inputs)
//  [144,912)    Xbig[s][i] = xh                      (single bf16 copy)
//  [912,1212)   WpT[d][j], ev[d]
//  [1212]       a64t[j]=A^64; E[t][j]=split(A^(t+1)); Q[j][i]=split(B A^(63-i))
//  [1213,1225)  Kmat[dlt][d] = sum_k S[dlt][k] Mf[k][d],  S = sum_j B A^dlt C'
//  [1225,1609)  zero ut
// ---------------------------------------------------------------------------
__global__ __launch_bounds__(256) void prep(const float* __restrict__ x,
                                            const float* __restrict__ Mi,
                                            const float* __restrict__ C,
                                            const float* __restrict__ Dv,
                                            const float* __restrict__ Mf,
                                            const float* __restrict__ Av,
                                            const float* __restrict__ Bv,
                                            unsigned short* __restrict__ Mbig,
                                            unsigned short* __restrict__ Xbig,
                                            float* __restrict__ WpT,
                                            float* __restrict__ evec,
                                            float* __restrict__ a64t,
                                            unsigned short* __restrict__ Ehi,
                                            unsigned short* __restrict__ Elo,
                                            unsigned short* __restrict__ Qhi,
                                            unsigned short* __restrict__ Qlo,
                                            float* __restrict__ Kmat,
                                            float* __restrict__ ut) {
    __shared__ float tl[64][65];
    __shared__ float S[64 * 24];
    int bid = blockIdx.x, t = threadIdx.x;
    if (bid < 144) {
        int i0 = (bid / 12) * 64, d0 = (bid % 12) * 64;
        int tx = t & 63, ty = t >> 6;
#pragma unroll
        for (int r = ty; r < 64; r += 4)
            tl[r][tx] = Mi[(i0 + r) * DM + d0 + tx];
        __syncthreads();
#pragma unroll
        for (int r = ty; r < 64; r += 4) {
            float v = tl[tx][r];                       // Mi[i0+tx][d0+r]
            unsigned short h = bf16_rn(v);
            unsigned short lo = bf16_rn(v - bf2f(h));
            unsigned short* row = Mbig + (size_t)(d0 + r) * GK2 + i0 + tx;
            row[0] = h; row[DM] = lo;
        }
    } else if (bid < 912) {
        int idx8 = (bid - 144) * 256 + t;              // 8 elems per thread
        int s = idx8 / (DM / 8), i0 = (idx8 % (DM / 8)) * 8;
        const float* xp = x + (size_t)s * DM + i0;
        float4 v0 = *(const float4*)xp;
        float4 v1 = *(const float4*)(xp + 4);
        float av[8] = {v0.x, v0.y, v0.z, v0.w, v1.x, v1.y, v1.z, v1.w};
        short8 hh;
#pragma unroll
        for (int q = 0; q < 8; ++q) hh[q] = (short)bf16_rn(av[q]);
        *(short8*)(Xbig + (size_t)s * DM + i0) = hh;
    } else if (bid < 1212) {
        int tid = (bid - 912) * 256 + t;
        if (tid < ST * DM) {
            int d = tid / ST, j = tid % ST;
            float s = 0.f;
#pragma unroll
            for (int k = 0; k < KF; ++k)
                s += (C[j * 2 * KF + k] + C[j * 2 * KF + KF + k]) * Mf[k * DM + d];
            WpT[tid] = s;
        }
        if (tid < DM) {
            float s = 0.f;
#pragma unroll
            for (int k = 0; k < KF; ++k)
                s += (Dv[k] + Dv[KF + k]) * Mf[k * DM + tid];
            evec[tid] = s;
        }
    } else if (bid == 1212) {
        if (t < KJ) {
            int j = t;
            bool ja = (j < ST);
            float a = ja ? Av[j] : 0.f;
            float b = ja ? Bv[j] : 0.f;
            float p = 1.f;
            for (int tt = 0; tt < 64; ++tt) {
                p *= a;                                // A^(tt+1)
                unsigned short h = bf16_rn(p);
                Ehi[tt * KJ + j] = h;
                Elo[tt * KJ + j] = bf16_rn(p - bf2f(h));
            }
            p *= a;                                    // A^65 (unused)
            float a2 = a * a, a4 = a2 * a2, a8 = a4 * a4;
            float a16 = a8 * a8, a32 = a16 * a16;
            a64t[j] = a32 * a32;
            if (j < NJ) {
                float pk = 1.f;                        // A^k
                for (int k = 0; k < 64; ++k) {
                    float v = b * pk;
                    unsigned short h = bf16_rn(v);
                    Qhi[j * 64 + (63 - k)] = h;
                    Qlo[j * 64 + (63 - k)] = bf16_rn(v - bf2f(h));
                    pk *= a;
                }
            }
        }
    } else if (bid < 1225) {
        int d0 = (bid - 1213) * 64;
        for (int e = t; e < 64 * KF; e += 256) {
            int dlt = e / KF, k = e % KF;
            float s = 0.f;
            for (int j = 0; j < ST; ++j) {
                float a = Av[j];
                float r = 1.f, bb = a;
                int n = dlt;
                while (n) { if (n & 1) r *= bb; bb *= bb; n >>= 1; }
                s += Bv[j] * r * (C[j * 2 * KF + k] + C[j * 2 * KF + KF + k]);
            }
            S[e] = s;
        }
        __syncthreads();
        for (int o = t; o < 64 * 64; o += 256) {
            int dlt = o >> 6, d = d0 + (o & 63);
            float s = 0.f;
#pragma unroll
            for (int k = 0; k < KF; ++k) s += S[dlt * KF + k] * Mf[k * DM + d];
            Kmat[dlt * DM + d] = s;
        }
    } else {
        int idx = (bid - 1225) * 256 + t;
        *(float4*)&ut[(size_t)idx * 4] = make_float4(0.f, 0.f, 0.f, 0.f);
    }
}

// ---------------------------------------------------------------------------
// MFMA GEMM, split-K x8, fp32 atomics: ut[d][s] += Mbig[d][:] . [xh|xh][s][:]
// 128x128 tile, BK=32, swizzled LDS (q' = (q + row>>1) & 3 kills 8-way bank
// conflict), async16 staging. Grid (96 tiles, 8 k-chunks).
// ---------------------------------------------------------------------------
__global__ __launch_bounds__(256) void gemm_mfma(const unsigned short* __restrict__ Mbig,
                                                 const unsigned short* __restrict__ Xbig,
                                                 float* __restrict__ ut) {
    __shared__ unsigned short As[128 * 32];
    __shared__ unsigned short Bs[128 * 32];
    int t = threadIdx.x;
    int tile = blockIdx.x;
    int d0 = (tile % (DM / 128)) * 128;
    int s0 = (tile / (DM / 128)) * 128;
    int k0base = blockIdx.y * KC2;
    int wave = t >> 6, lane = t & 63;
    int wm = (wave & 1) * 64, wn = (wave >> 1) * 64;
    int m16 = lane & 15, quad = lane >> 4;
    // staging: lane-id L in {t, t+256}; LDS slot L*16B = (row=L>>2, q'=L&3);
    // source k16 q = (q' - (row>>1)) & 3
    int r0 = t >> 2,        q0 = ((t & 3) - (t >> 3)) & 3;
    int r1 = (t + 256) >> 2, q1 = (((t + 256) & 3) - ((t + 256) >> 3)) & 3;
    float4v acc[4][4];
#pragma unroll
    for (int mt = 0; mt < 4; ++mt)
#pragma unroll
        for (int nt = 0; nt < 4; ++nt) acc[mt][nt] = (float4v){0.f, 0.f, 0.f, 0.f};
    for (int k0 = k0base; k0 < k0base + KC2; k0 += 32) {
        int kb = k0 - (k0 >= DM ? DM : 0);             // Xbig has one 768-wide copy
        __syncthreads();
        async16(&Mbig[(size_t)(d0 + r0) * GK2 + k0 + q0 * 8], &As[(size_t)t * 8]);
        async16(&Xbig[(size_t)(s0 + r0) * DM  + kb + q0 * 8], &Bs[(size_t)t * 8]);
        async16(&Mbig[(size_t)(d0 + r1) * GK2 + k0 + q1 * 8], &As[(size_t)(t + 256) * 8]);
        async16(&Xbig[(size_t)(s0 + r1) * DM  + kb + q1 * 8], &Bs[(size_t)(t + 256) * 8]);
        __syncthreads();
        short8 af[4], bf[4];
#pragma unroll
        for (int mt = 0; mt < 4; ++mt) {
            int row = wm + mt * 16 + m16;
            int qp = (quad + (row >> 1)) & 3;
            af[mt] = *(short8*)&As[row * 32 + qp * 8];
        }
#pragma unroll
        for (int nt = 0; nt < 4; ++nt) {
            int row = wn + nt * 16 + m16;
            int qp = (quad + (row >> 1)) & 3;
            bf[nt] = *(short8*)&Bs[row * 32 + qp * 8];
        }
#pragma unroll
        for (int mt = 0; mt < 4; ++mt)
#pragma unroll
            for (int nt = 0; nt < 4; ++nt)
                acc[mt][nt] = __builtin_amdgcn_mfma_f32_16x16x32_bf16(af[mt], bf[nt], acc[mt][nt], 0, 0, 0);
    }
#pragma unroll
    for (int mt = 0; mt < 4; ++mt)
#pragma unroll
        for (int nt = 0; nt < 4; ++nt) {
            int dd = d0 + wm + mt * 16 + quad * 4;
            int ss = s0 + wn + nt * 16 + m16;
#pragma unroll
            for (int i = 0; i < 4; ++i)
                atomAddF(&ut[(size_t)(dd + i) * SEQ + ss], acc[mt][nt][i]);
        }
}

// ---------------------------------------------------------------------------
// hscanG_f: fused intra-Toeplitz + hloc GEMM + chunk scan + G write.
// Block = 2 channels (d0 = 2*bx), 256 threads. Phases share smem[7680]:
//  P1 stage u (64 rows x 68 pad) + kk (2x64)      -> P2 intra -> yintra
//  P3 hloc MFMA (ut from global) -> hl[64][120]   -> P4 scan  -> Ghi/Glo
// ---------------------------------------------------------------------------
__global__ __launch_bounds__(256) void hscanG_f(const float* __restrict__ ut,
                                                const unsigned short* __restrict__ Qhi,
                                                const unsigned short* __restrict__ Qlo,
                                                const float* __restrict__ WpT,
                                                const float* __restrict__ a64t,
                                                const float* __restrict__ Kmat,
                                                const float* __restrict__ evec,
                                                float* __restrict__ yintra,
                                                unsigned short* __restrict__ Ghi,
                                                unsigned short* __restrict__ Glo) {
    __shared__ float smem[7680];
    const int t = threadIdx.x;
    const int d0 = blockIdx.x * 2;
    const int m0 = blockIdx.x * 64;          // ut viewed as (768*32) x 64
    // ---- P1: stage u[2][2048] as [dc=dloc*32+c][68] + kk ----
#pragma unroll
    for (int it = 0; it < 4; ++it) {
        int id = t + it * 256;               // 1024 float4 units
        int dl = id >> 9, pos = (id & 511) * 4;
        int dc = dl * 32 + (pos >> 6), ii = pos & 63;
        *(float4*)&smem[dc * 68 + ii] = *(const float4*)&ut[(size_t)(d0 + dl) * SEQ + pos];
    }
    if (t < 128) smem[4352 + t] = Kmat[(t & 63) * DM + d0 + (t >> 6)];
    __syncthreads();
    // ---- P2: intra Toeplitz + feedthrough (wave = t-group -> uniform bounds)
    {
        int tg = t >> 6, lane = t & 63;
        int dloc = lane >> 5, c = lane & 31;
        int tbase = tg * 16;
        const float* uc = &smem[(dloc * 32 + c) * 68];
        const float* kk = &smem[4352 + dloc * 64];
        float e = evec[d0 + dloc];
        float yv[16];
#pragma unroll
        for (int i = 0; i < 16; ++i) yv[i] = e * uc[tbase + i];
        for (int dlt = 0; dlt <= tbase + 15; ++dlt) {
            float kv = kk[dlt];
            int imin = dlt - tbase; if (imin < 0) imin = 0;
            for (int i = imin; i < 16; ++i)
                yv[i] = fmaf(kv, uc[tbase + i - dlt], yv[i]);
        }
        float* yo = yintra + (size_t)(d0 + dloc) * SEQ + c * 64 + tbase;
#pragma unroll
        for (int q = 0; q < 4; ++q)
            *(float4*)(yo + q * 4) = make_float4(yv[q * 4], yv[q * 4 + 1], yv[q * 4 + 2], yv[q * 4 + 3]);
    }
    __syncthreads();
    // ---- P3: hloc = u(64x64) @ Q^T -> hl[64][120] (overwrites P1 region) ----
    {
        int wave = t >> 6, lane = t & 63;
        int m16 = lane & 15, quad = lane >> 4;
        float4v acc[7];
#pragma unroll
        for (int nt = 0; nt < 7; ++nt) acc[nt] = (float4v){0.f, 0.f, 0.f, 0.f};
#pragma unroll
        for (int ks = 0; ks < 2; ++ks) {
            const float* ap = ut + (size_t)(m0 + wave * 16 + m16) * 64 + ks * 32 + quad * 8;
            float4 a0 = *(const float4*)ap;
            float4 a1 = *(const float4*)(ap + 4);
            float av[8] = {a0.x, a0.y, a0.z, a0.w, a1.x, a1.y, a1.z, a1.w};
            short8 ah, al;
#pragma unroll
            for (int q = 0; q < 8; ++q) {
                unsigned short h = bf16_rn(av[q]);
                ah[q] = (short)h;
                al[q] = (short)bf16_rn(av[q] - bf2f(h));
            }
#pragma unroll
            for (int nt = 0; nt < 7; ++nt) {
                int qoff = (nt * 16 + m16) * 64 + ks * 32 + quad * 8;
                short8 bh = *(const short8*)(Qhi + qoff);
                short8 bl = *(const short8*)(Qlo + qoff);
                acc[nt] = __builtin_amdgcn_mfma_f32_16x16x32_bf16(ah, bh, acc[nt], 0, 0, 0);
                acc[nt] = __builtin_amdgcn_mfma_f32_16x16x32_bf16(ah, bl, acc[nt], 0, 0, 0);
                acc[nt] = __builtin_amdgcn_mfma_f32_16x16x32_bf16(al, bh, acc[nt], 0, 0, 0);
            }
        }
        __syncthreads();                      // P2 readers done before overwrite
#pragma unroll
        for (int nt = 0; nt < 7; ++nt)
#pragma unroll
            for (int i = 0; i < 4; ++i)
                smem[(wave * 16 + quad * 4 + i) * 120 + nt * 16 + m16] = acc[nt][i];
    }
    __syncthreads();
    // ---- P4: inter-chunk scan + G = split(w * hs) ----
    {
        int j = t & 127, dloc = t >> 7;
        int d = d0 + dloc;
        bool ja = (j < ST);
        float a64 = a64t[j];
        float w = ja ? WpT[d * ST + j] : 0.f;
        float hs = 0.f;
        for (int c = 0; c < NC; ++c) {
            float g = w * hs;
            unsigned short gh = bf16_rn(g);
            size_t go = ((size_t)c * DM + d) * KJ + j;
            Ghi[go] = gh;
            Glo[go] = bf16_rn(g - bf2f(gh));
            float add = ja ? smem[(dloc * 32 + c) * 120 + j] : 0.f;
            hs = fmaf(a64, hs, add);
        }
    }
}

// ---------------------------------------------------------------------------
// inter: out[c*64+t][d] = (E @ G_c)[t][d] + yintra[d][c*64+t]
// Block = (chunk c, 64-wide d tile): M=64, N=64, K=128, 4 waves (16-d strips).
// ---------------------------------------------------------------------------
__global__ __launch_bounds__(256) void inter(const unsigned short* __restrict__ Ehi,
                                             const unsigned short* __restrict__ Elo,
                                             const unsigned short* __restrict__ Ghi,
                                             const unsigned short* __restrict__ Glo,
                                             const float* __restrict__ yintra,
                                             float* __restrict__ out) {
    __shared__ float yl[64][68];
    int c = blockIdx.x;
    int d0 = blockIdx.y * 64;
    int t = threadIdx.x;
#pragma unroll
    for (int it = 0; it < 4; ++it) {
        int idx = t + it * 256;              // 1024 float4 units
        int row = idx >> 4, col4 = (idx & 15) * 4;
        float4 v = *(const float4*)&yintra[(size_t)(d0 + row) * SEQ + c * 64 + col4];
        yl[col4 + 0][row] = v.x;
        yl[col4 + 1][row] = v.y;
        yl[col4 + 2][row] = v.z;
        yl[col4 + 3][row] = v.w;
    }
    __syncthreads();
    int wave = t >> 6, lane = t & 63;
    int wn = wave * 16;
    int m16 = lane & 15, quad = lane >> 4;
    float4v acc[4];
#pragma unroll
    for (int mt = 0; mt < 4; ++mt) acc[mt] = (float4v){0.f, 0.f, 0.f, 0.f};
#pragma unroll
    for (int ks = 0; ks < 4; ++ks) {
        size_t gb = ((size_t)c * DM + d0 + wn + m16) * KJ + ks * 32 + quad * 8;
        short8 bh = *(const short8*)(Ghi + gb);
        short8 bl = *(const short8*)(Glo + gb);
#pragma unroll
        for (int mt = 0; mt < 4; ++mt) {
            int eo = (mt * 16 + m16) * KJ + ks * 32 + quad * 8;
            short8 ah = *(const short8*)(Ehi + eo);
            short8 al = *(const short8*)(Elo + eo);
            acc[mt] = __builtin_amdgcn_mfma_f32_16x16x32_bf16(ah, bh, acc[mt], 0, 0, 0);
            acc[mt] = __builtin_amdgcn_mfma_f32_16x16x32_bf16(ah, bl, acc[mt], 0, 0, 0);
            acc[mt] = __builtin_amdgcn_mfma_f32_16x16x32_bf16(al, bh, acc[mt], 0, 0, 0);
        }
    }
#pragma unroll
    for (int mt = 0; mt < 4; ++mt) {
        int tt = mt * 16 + quad * 4;
        int dcol = wn + m16;
#pragma unroll
        for (int i = 0; i < 4; ++i) {
            float v = acc[mt][i] + yl[tt + i][dcol];
            out[(size_t)(c * 64 + tt + i) * DM + d0 + dcol] = v;
        }
    }
}

extern "C" void kernel_launch(void* const* d_in, const int* in_sizes, int n_in,
                              void* d_out, int out_size, void* d_ws, size_t ws_size,
                              hipStream_t stream) {
    const float* x  = (const float*)d_in[0];
    const float* Mi = (const float*)d_in[2];
    const float* Mf = (const float*)d_in[3];
    const float* Av = (const float*)d_in[4];
    const float* Bv = (const float*)d_in[5];
    const float* C  = (const float*)d_in[6];
    const float* Dv = (const float*)d_in[7];
    float* out = (float*)d_out;

    float* ut     = (float*)d_ws;                         // 768*2048
    float* WpT    = ut + (size_t)DM * SEQ;                // 768*100
    float* ev     = WpT + DM * ST;                        // 768
    float* a64t   = ev + DM;                              // 128
    float* Kmat   = a64t + KJ;                            // 64*768
    float* yintra = Kmat + 64 * DM;                       // 768*2048
    unsigned short* Mbig = (unsigned short*)(yintra + (size_t)DM * SEQ); // 768*1536
    unsigned short* Xbig = Mbig + (size_t)DM * GK2;       // 2048*768
    unsigned short* Ehi  = Xbig + (size_t)SEQ * DM;       // 64*128
    unsigned short* Elo  = Ehi + 64 * KJ;
    unsigned short* Qhi  = Elo + 64 * KJ;                 // 112*64
    unsigned short* Qlo  = Qhi + NJ * 64;
    unsigned short* Ghi  = Qlo + NJ * 64;                 // 32*768*128
    unsigned short* Glo  = Ghi + (size_t)NC * DM * KJ;

    prep<<<1609, 256, 0, stream>>>(x, Mi, C, Dv, Mf, Av, Bv, Mbig, Xbig,
                                   WpT, ev, a64t, Ehi, Elo, Qhi, Qlo, Kmat, ut);
    gemm_mfma<<<dim3((DM / 128) * (SEQ / 128), KS2), 256, 0, stream>>>(Mbig, Xbig, ut);
    hscanG_f<<<DM / 2, 256, 0, stream>>>(ut, Qhi, Qlo, WpT, a64t, Kmat, ev,
                                         yintra, Ghi, Glo);
    inter<<<dim3(NC, DM / 64), 256, 0, stream>>>(Ehi, Elo, Ghi, Glo, yintra, out);
}

// Round 7
// 166.781 us; speedup vs baseline: 2.6562x; 2.6562x over previous
//
#include <hip/hip_runtime.h>

#define SEQ   2048
#define DM    768
#define ST    100
#define KF    24
#define NC    32      // SEQ / 64
#define KJ    128     // padded state dim (inter-GEMM K)
#define NJ    112     // padded state dim (hloc-GEMM N)
#define GK2   1536    // 2 * DM  (bf16x2 split K for input GEMM)
#define KS2   8
#define KC2   192     // GK2 / KS2

using short8  = __attribute__((ext_vector_type(8))) short;
using float4v = __attribute__((ext_vector_type(4))) float;

__device__ __forceinline__ unsigned short bf16_rn(float x) {
    unsigned int u = __float_as_uint(x);
    unsigned int r = u + 0x7FFFu + ((u >> 16) & 1u);
    return (unsigned short)(r >> 16);
}
__device__ __forceinline__ float bf2f(unsigned short h) {
    return __uint_as_float(((unsigned int)h) << 16);
}
__device__ __forceinline__ void async16(const void* g, void* l) {
    __builtin_amdgcn_global_load_lds(
        (const __attribute__((address_space(1))) unsigned int*)g,
        (__attribute__((address_space(3))) unsigned int*)l, 16, 0, 0);
}
__device__ __forceinline__ void atomAddF(float* p, float v) {
#if __has_builtin(__builtin_amdgcn_global_atomic_fadd_f32)
    __builtin_amdgcn_global_atomic_fadd_f32(
        (__attribute__((address_space(1))) float*)p, v);
#else
    unsafeAtomicAdd(p, v);
#endif
}

// ---------------------------------------------------------------------------
// prep: block ranges (R5 structure, bf16x2 M / single-copy X):
//  [0,144)      Mbig[d][k] = [Mh^T | Ml^T]
//  [144,912)    Xbig[s][i] = bf16(x)           (16B stores)
//  [912,1212)   WpT[d][j] = sum_k (C[j,k]+C[j,k+24])*Mf[k,d];  ev[d]
//  [1212]       Apow[delta][j] = A_j^delta, delta = 0..64
// ---------------------------------------------------------------------------
__global__ __launch_bounds__(256) void prep(const float* __restrict__ x,
                                            const float* __restrict__ Mi,
                                            const float* __restrict__ C,
                                            const float* __restrict__ Dv,
                                            const float* __restrict__ Mf,
                                            const float* __restrict__ Av,
                                            unsigned short* __restrict__ Mbig,
                                            unsigned short* __restrict__ Xbig,
                                            float* __restrict__ WpT,
                                            float* __restrict__ evec,
                                            float* __restrict__ Apow) {
    __shared__ float tl[64][65];
    int bid = blockIdx.x, t = threadIdx.x;
    if (bid < 144) {
        int i0 = (bid / 12) * 64, d0 = (bid % 12) * 64;
        int tx = t & 63, ty = t >> 6;
#pragma unroll
        for (int r = ty; r < 64; r += 4)
            tl[r][tx] = Mi[(i0 + r) * DM + d0 + tx];
        __syncthreads();
#pragma unroll
        for (int r = ty; r < 64; r += 4) {
            float v = tl[tx][r];                       // Mi[i0+tx][d0+r]
            unsigned short h = bf16_rn(v);
            unsigned short lo = bf16_rn(v - bf2f(h));
            unsigned short* row = Mbig + (size_t)(d0 + r) * GK2 + i0 + tx;
            row[0] = h; row[DM] = lo;
        }
    } else if (bid < 912) {
        int idx8 = (bid - 144) * 256 + t;              // 8 elems per thread
        int s = idx8 / (DM / 8), i0 = (idx8 % (DM / 8)) * 8;
        const float* xp = x + (size_t)s * DM + i0;
        float4 v0 = *(const float4*)xp;
        float4 v1 = *(const float4*)(xp + 4);
        float av[8] = {v0.x, v0.y, v0.z, v0.w, v1.x, v1.y, v1.z, v1.w};
        short8 hh;
#pragma unroll
        for (int q = 0; q < 8; ++q) hh[q] = (short)bf16_rn(av[q]);
        *(short8*)(Xbig + (size_t)s * DM + i0) = hh;
    } else if (bid < 1212) {
        int tid = (bid - 912) * 256 + t;
        if (tid < ST * DM) {
            int d = tid / ST, j = tid % ST;
            float s = 0.f;
#pragma unroll
            for (int k = 0; k < KF; ++k)
                s += (C[j * 2 * KF + k] + C[j * 2 * KF + KF + k]) * Mf[k * DM + d];
            WpT[tid] = s;
        }
        if (tid < DM) {
            float s = 0.f;
#pragma unroll
            for (int k = 0; k < KF; ++k)
                s += (Dv[k] + Dv[KF + k]) * Mf[k * DM + tid];
            evec[tid] = s;
        }
    } else {
        if (t < ST) {
            float a = Av[t];
            float p = 1.f;
            for (int dlt = 0; dlt <= 64; ++dlt) { Apow[dlt * ST + t] = p; p *= a; }
        }
    }
}

// ---------------------------------------------------------------------------
// tables: Kmat[delta][d] = sum_j B_j A_j^delta WpT[d][j]  (64x768 fp32)
//         Ehi/Elo[t][j]  = split(A_j^(t+1))               (64x128 bf16)
//         Qhi/Qlo[j][i]  = split(B_j A_j^(63-i))          (112x64 bf16)
// ---------------------------------------------------------------------------
__global__ __launch_bounds__(256) void tables(const float* __restrict__ Bv,
                                              const float* __restrict__ Apow,
                                              const float* __restrict__ WpT,
                                              float* __restrict__ Kmat,
                                              unsigned short* __restrict__ Ehi,
                                              unsigned short* __restrict__ Elo,
                                              unsigned short* __restrict__ Qhi,
                                              unsigned short* __restrict__ Qlo) {
    int tid = blockIdx.x * 256 + threadIdx.x;
    if (tid < 64 * DM) {
        int dlt = tid / DM, d = tid % DM;
        float s = 0.f;
        for (int j = 0; j < ST; ++j)
            s += Bv[j] * Apow[dlt * ST + j] * WpT[d * ST + j];
        Kmat[dlt * DM + d] = s;
    } else if (tid < 64 * DM + 64 * KJ) {
        int r = tid - 64 * DM;
        int tt = r >> 7, j = r & 127;
        float v = (j < ST) ? Apow[(tt + 1) * ST + j] : 0.f;
        unsigned short h = bf16_rn(v);
        unsigned short lo = bf16_rn(v - bf2f(h));
        Ehi[tt * KJ + j] = h;
        Elo[tt * KJ + j] = lo;
    } else {
        int r = tid - 64 * DM - 64 * KJ;
        if (r < NJ * 64) {
            int j = r >> 6, i = r & 63;
            float v = (j < ST) ? Bv[j] * Apow[(63 - i) * ST + j] : 0.f;
            unsigned short h = bf16_rn(v);
            unsigned short lo = bf16_rn(v - bf2f(h));
            Qhi[j * 64 + i] = h;
            Qlo[j * 64 + i] = lo;
        }
    }
}

// ---------------------------------------------------------------------------
// MFMA GEMM, split-K x8, fp32 atomics: ut[d][s] += [Mh|Ml][d][:] . [xh|xh][s][:]
// 128x128 tile, BK=32, swizzled LDS (q' = (q + row>>1) & 3), async16 staging.
// ---------------------------------------------------------------------------
__global__ __launch_bounds__(256) void gemm_mfma(const unsigned short* __restrict__ Mbig,
                                                 const unsigned short* __restrict__ Xbig,
                                                 float* __restrict__ ut) {
    __shared__ unsigned short As[128 * 32];
    __shared__ unsigned short Bs[128 * 32];
    int t = threadIdx.x;
    int tile = blockIdx.x;
    int d0 = (tile % (DM / 128)) * 128;
    int s0 = (tile / (DM / 128)) * 128;
    int k0base = blockIdx.y * KC2;
    int wave = t >> 6, lane = t & 63;
    int wm = (wave & 1) * 64, wn = (wave >> 1) * 64;
    int m16 = lane & 15, quad = lane >> 4;
    int r0 = t >> 2,         q0 = ((t & 3) - (t >> 3)) & 3;
    int r1 = (t + 256) >> 2, q1 = (((t + 256) & 3) - ((t + 256) >> 3)) & 3;
    float4v acc[4][4];
#pragma unroll
    for (int mt = 0; mt < 4; ++mt)
#pragma unroll
        for (int nt = 0; nt < 4; ++nt) acc[mt][nt] = (float4v){0.f, 0.f, 0.f, 0.f};
    for (int k0 = k0base; k0 < k0base + KC2; k0 += 32) {
        int kb = k0 - (k0 >= DM ? DM : 0);             // Xbig has one 768-wide copy
        __syncthreads();
        async16(&Mbig[(size_t)(d0 + r0) * GK2 + k0 + q0 * 8], &As[(size_t)t * 8]);
        async16(&Xbig[(size_t)(s0 + r0) * DM  + kb + q0 * 8], &Bs[(size_t)t * 8]);
        async16(&Mbig[(size_t)(d0 + r1) * GK2 + k0 + q1 * 8], &As[(size_t)(t + 256) * 8]);
        async16(&Xbig[(size_t)(s0 + r1) * DM  + kb + q1 * 8], &Bs[(size_t)(t + 256) * 8]);
        __syncthreads();
        short8 af[4], bf[4];
#pragma unroll
        for (int mt = 0; mt < 4; ++mt) {
            int row = wm + mt * 16 + m16;
            int qp = (quad + (row >> 1)) & 3;
            af[mt] = *(short8*)&As[row * 32 + qp * 8];
        }
#pragma unroll
        for (int nt = 0; nt < 4; ++nt) {
            int row = wn + nt * 16 + m16;
            int qp = (quad + (row >> 1)) & 3;
            bf[nt] = *(short8*)&Bs[row * 32 + qp * 8];
        }
#pragma unroll
        for (int mt = 0; mt < 4; ++mt)
#pragma unroll
            for (int nt = 0; nt < 4; ++nt)
                acc[mt][nt] = __builtin_amdgcn_mfma_f32_16x16x32_bf16(af[mt], bf[nt], acc[mt][nt], 0, 0, 0);
    }
#pragma unroll
    for (int mt = 0; mt < 4; ++mt)
#pragma unroll
        for (int nt = 0; nt < 4; ++nt) {
            int dd = d0 + wm + mt * 16 + quad * 4;
            int ss = s0 + wn + nt * 16 + m16;
#pragma unroll
            for (int i = 0; i < 4; ++i)
                atomAddF(&ut[(size_t)(dd + i) * SEQ + ss], acc[mt][nt][i]);
        }
}

// ---------------------------------------------------------------------------
// hscanG: hloc GEMM (ut rows x Q) + 32-step chunk scan + G write. (R5 exact)
// ---------------------------------------------------------------------------
__global__ __launch_bounds__(256) void hscanG(const float* __restrict__ ut,
                                              const unsigned short* __restrict__ Qhi,
                                              const unsigned short* __restrict__ Qlo,
                                              const float* __restrict__ WpT,
                                              const float* __restrict__ Apow,
                                              unsigned short* __restrict__ Ghi,
                                              unsigned short* __restrict__ Glo) {
    __shared__ float hl[64][120];
    int m0 = blockIdx.x * 64;
    int wave = threadIdx.x >> 6, lane = threadIdx.x & 63;
    int m16 = lane & 15, quad = lane >> 4;
    float4v acc[7];
#pragma unroll
    for (int nt = 0; nt < 7; ++nt) acc[nt] = (float4v){0.f, 0.f, 0.f, 0.f};
#pragma unroll
    for (int ks = 0; ks < 2; ++ks) {
        const float* ap = ut + (size_t)(m0 + wave * 16 + m16) * 64 + ks * 32 + quad * 8;
        float4 a0 = *(const float4*)ap;
        float4 a1 = *(const float4*)(ap + 4);
        float av[8] = {a0.x, a0.y, a0.z, a0.w, a1.x, a1.y, a1.z, a1.w};
        short8 ah, al;
#pragma unroll
        for (int q = 0; q < 8; ++q) {
            unsigned short h = bf16_rn(av[q]);
            ah[q] = (short)h;
            al[q] = (short)bf16_rn(av[q] - bf2f(h));
        }
#pragma unroll
        for (int nt = 0; nt < 7; ++nt) {
            int qoff = (nt * 16 + m16) * 64 + ks * 32 + quad * 8;
            short8 bh = *(const short8*)(Qhi + qoff);
            short8 bl = *(const short8*)(Qlo + qoff);
            acc[nt] = __builtin_amdgcn_mfma_f32_16x16x32_bf16(ah, bh, acc[nt], 0, 0, 0);
            acc[nt] = __builtin_amdgcn_mfma_f32_16x16x32_bf16(ah, bl, acc[nt], 0, 0, 0);
            acc[nt] = __builtin_amdgcn_mfma_f32_16x16x32_bf16(al, bh, acc[nt], 0, 0, 0);
        }
    }
#pragma unroll
    for (int nt = 0; nt < 7; ++nt)
#pragma unroll
        for (int i = 0; i < 4; ++i)
            hl[wave * 16 + quad * 4 + i][nt * 16 + m16] = acc[nt][i];
    __syncthreads();

    int j = threadIdx.x & 127, dloc = threadIdx.x >> 7;
    int d = blockIdx.x * 2 + dloc;
    bool ja = (j < ST);
    float a64 = ja ? Apow[64 * ST + j] : 0.f;
    float w   = ja ? WpT[d * ST + j] : 0.f;
    float hs = 0.f;
    for (int c = 0; c < NC; ++c) {
        float g = ja ? (w * hs) : 0.f;
        unsigned short gh = bf16_rn(g);
        unsigned short gl = bf16_rn(g - bf2f(gh));
        size_t go = ((size_t)c * DM + d) * KJ + j;
        Ghi[go] = gh;
        Glo[go] = gl;
        float add = ja ? hl[dloc * 32 + c][j] : 0.f;
        hs = fmaf(a64, hs, add);
    }
}

// ---------------------------------------------------------------------------
// intra: register-resident causal Toeplitz per (d, chunk) + feedthrough. (R5)
// ---------------------------------------------------------------------------
__global__ __launch_bounds__(64) void intra(const float* __restrict__ ut,
                                            const float* __restrict__ Kmat,
                                            const float* __restrict__ evec,
                                            float* __restrict__ yintra) {
    int lane = threadIdx.x;
    int d = blockIdx.x * 2 + (lane >> 5);
    int c = lane & 31;
    const float* u = ut + (size_t)d * SEQ + c * 64;
    float uu[64];
#pragma unroll
    for (int q = 0; q < 16; ++q) {
        float4 v = *(const float4*)(u + q * 4);
        uu[q * 4 + 0] = v.x; uu[q * 4 + 1] = v.y;
        uu[q * 4 + 2] = v.z; uu[q * 4 + 3] = v.w;
    }
    float e = evec[d];
    float y[64];
#pragma unroll
    for (int t = 0; t < 64; ++t) y[t] = e * uu[t];
#pragma unroll
    for (int dlt = 0; dlt < 64; ++dlt) {
        float k = Kmat[dlt * DM + d];
#pragma unroll
        for (int t = dlt; t < 64; ++t)
            y[t] = fmaf(k, uu[t - dlt], y[t]);
    }
    float* yo = yintra + (size_t)d * SEQ + c * 64;
#pragma unroll
    for (int q = 0; q < 16; ++q) {
        float4 v = make_float4(y[q * 4 + 0], y[q * 4 + 1], y[q * 4 + 2], y[q * 4 + 3]);
        *(float4*)(yo + q * 4) = v;
    }
}

// ---------------------------------------------------------------------------
// inter: out[c*64+t][d] = (E @ G_c)[t][d] + yintra[d][c*64+t]   (R5 exact)
// ---------------------------------------------------------------------------
__global__ __launch_bounds__(256) void inter(const unsigned short* __restrict__ Ehi,
                                             const unsigned short* __restrict__ Elo,
                                             const unsigned short* __restrict__ Ghi,
                                             const unsigned short* __restrict__ Glo,
                                             const float* __restrict__ yintra,
                                             float* __restrict__ out) {
    __shared__ float yl[64][129];
    int c = blockIdx.x;
    int d0 = blockIdx.y * 128;
    int wave = threadIdx.x >> 6, lane = threadIdx.x & 63;
    int wn = wave * 32;
    int m16 = lane & 15, quad = lane >> 4;
#pragma unroll
    for (int it = 0; it < 8; ++it) {
        int idx = threadIdx.x + it * 256;
        int row = idx >> 4, col4 = (idx & 15) * 4;
        float4 v = *(const float4*)&yintra[(size_t)(d0 + row) * SEQ + c * 64 + col4];
        yl[col4 + 0][row] = v.x;
        yl[col4 + 1][row] = v.y;
        yl[col4 + 2][row] = v.z;
        yl[col4 + 3][row] = v.w;
    }
    float4v acc[4][2];
#pragma unroll
    for (int mt = 0; mt < 4; ++mt)
#pragma unroll
        for (int nt = 0; nt < 2; ++nt) acc[mt][nt] = (float4v){0.f, 0.f, 0.f, 0.f};
#pragma unroll
    for (int ks = 0; ks < 4; ++ks) {
        short8 bh[2], bl[2];
#pragma unroll
        for (int nt = 0; nt < 2; ++nt) {
            size_t ga = ((size_t)c * DM + d0 + wn + nt * 16 + m16) * KJ + ks * 32 + quad * 8;
            bh[nt] = *(const short8*)(Ghi + ga);
            bl[nt] = *(const short8*)(Glo + ga);
        }
#pragma unroll
        for (int mt = 0; mt < 4; ++mt) {
            int eo = (mt * 16 + m16) * KJ + ks * 32 + quad * 8;
            short8 ah = *(const short8*)(Ehi + eo);
            short8 al = *(const short8*)(Elo + eo);
#pragma unroll
            for (int nt = 0; nt < 2; ++nt) {
                acc[mt][nt] = __builtin_amdgcn_mfma_f32_16x16x32_bf16(ah, bh[nt], acc[mt][nt], 0, 0, 0);
                acc[mt][nt] = __builtin_amdgcn_mfma_f32_16x16x32_bf16(ah, bl[nt], acc[mt][nt], 0, 0, 0);
                acc[mt][nt] = __builtin_amdgcn_mfma_f32_16x16x32_bf16(al, bh[nt], acc[mt][nt], 0, 0, 0);
            }
        }
    }
    __syncthreads();
#pragma unroll
    for (int mt = 0; mt < 4; ++mt)
#pragma unroll
        for (int nt = 0; nt < 2; ++nt) {
            int tt = mt * 16 + quad * 4;
            int dcol = wn + nt * 16 + m16;
#pragma unroll
            for (int i = 0; i < 4; ++i) {
                float v = acc[mt][nt][i] + yl[tt + i][dcol];
                out[(size_t)(c * 64 + tt + i) * DM + d0 + dcol] = v;
            }
        }
}

extern "C" void kernel_launch(void* const* d_in, const int* in_sizes, int n_in,
                              void* d_out, int out_size, void* d_ws, size_t ws_size,
                              hipStream_t stream) {
    const float* x  = (const float*)d_in[0];
    const float* Mi = (const float*)d_in[2];
    const float* Mf = (const float*)d_in[3];
    const float* Av = (const float*)d_in[4];
    const float* Bv = (const float*)d_in[5];
    const float* C  = (const float*)d_in[6];
    const float* Dv = (const float*)d_in[7];
    float* out = (float*)d_out;

    float* ut     = (float*)d_ws;                         // 768*2048
    float* WpT    = ut + (size_t)DM * SEQ;                // 768*100
    float* ev     = WpT + DM * ST;                        // 768
    float* Apow   = ev + DM;                              // 65*100
    float* Kmat   = Apow + 65 * ST;                       // 64*768
    float* yintra = Kmat + 64 * DM;                       // 768*2048
    unsigned short* Mbig = (unsigned short*)(yintra + (size_t)DM * SEQ); // 768*1536
    unsigned short* Xbig = Mbig + (size_t)DM * GK2;       // 2048*768
    unsigned short* Ehi  = Xbig + (size_t)SEQ * DM;       // 64*128
    unsigned short* Elo  = Ehi + 64 * KJ;
    unsigned short* Qhi  = Elo + 64 * KJ;                 // 112*64
    unsigned short* Qlo  = Qhi + NJ * 64;
    unsigned short* Ghi  = Qlo + NJ * 64;                 // 32*768*128
    unsigned short* Glo  = Ghi + (size_t)NC * DM * KJ;

    hipMemsetAsync(ut, 0, (size_t)DM * SEQ * sizeof(float), stream);
    prep<<<1213, 256, 0, stream>>>(x, Mi, C, Dv, Mf, Av, Mbig, Xbig, WpT, ev, Apow);
    tables<<<252, 256, 0, stream>>>(Bv, Apow, WpT, Kmat, Ehi, Elo, Qhi, Qlo);
    gemm_mfma<<<dim3((DM / 128) * (SEQ / 128), KS2), 256, 0, stream>>>(Mbig, Xbig, ut);
    hscanG<<<384, 256, 0, stream>>>(ut, Qhi, Qlo, WpT, Apow, Ghi, Glo);
    intra<<<384, 64, 0, stream>>>(ut, Kmat, ev, yintra);
    inter<<<dim3(NC, DM / 128), 256, 0, stream>>>(Ehi, Elo, Ghi, Glo, yintra, out);
}

// Round 8
// 138.675 us; speedup vs baseline: 3.1945x; 1.2027x over previous
//
#include <hip/hip_runtime.h>

#define SEQ   2048
#define DM    768
#define ST    100
#define KF    24
#define NC    32      // SEQ / 64
#define KJ    128     // padded state dim (inter-GEMM K)
#define NJ    112     // padded state dim (hloc-GEMM N)
#define GK2   1536    // 2 * DM  (bf16x2 split K for input GEMM)

using short8  = __attribute__((ext_vector_type(8))) short;
using float4v = __attribute__((ext_vector_type(4))) float;

__device__ __forceinline__ unsigned short bf16_rn(float x) {
    unsigned int u = __float_as_uint(x);
    unsigned int r = u + 0x7FFFu + ((u >> 16) & 1u);
    return (unsigned short)(r >> 16);
}
__device__ __forceinline__ float bf2f(unsigned short h) {
    return __uint_as_float(((unsigned int)h) << 16);
}
__device__ __forceinline__ void async16(const void* g, void* l) {
    __builtin_amdgcn_global_load_lds(
        (const __attribute__((address_space(1))) unsigned int*)g,
        (__attribute__((address_space(3))) unsigned int*)l, 16, 0, 0);
}

// ---------------------------------------------------------------------------
// prep: block ranges (unchanged from R7):
//  [0,144)      Mbig[d][k] = [Mh^T | Ml^T]
//  [144,912)    Xbig[s][i] = bf16(x)           (16B stores)
//  [912,1212)   WpT[d][j] = sum_k (C[j,k]+C[j,k+24])*Mf[k,d];  ev[d]
//  [1212]       Apow[delta][j] = A_j^delta, delta = 0..64
// ---------------------------------------------------------------------------
__global__ __launch_bounds__(256) void prep(const float* __restrict__ x,
                                            const float* __restrict__ Mi,
                                            const float* __restrict__ C,
                                            const float* __restrict__ Dv,
                                            const float* __restrict__ Mf,
                                            const float* __restrict__ Av,
                                            unsigned short* __restrict__ Mbig,
                                            unsigned short* __restrict__ Xbig,
                                            float* __restrict__ WpT,
                                            float* __restrict__ evec,
                                            float* __restrict__ Apow) {
    __shared__ float tl[64][65];
    int bid = blockIdx.x, t = threadIdx.x;
    if (bid < 144) {
        int i0 = (bid / 12) * 64, d0 = (bid % 12) * 64;
        int tx = t & 63, ty = t >> 6;
#pragma unroll
        for (int r = ty; r < 64; r += 4)
            tl[r][tx] = Mi[(i0 + r) * DM + d0 + tx];
        __syncthreads();
#pragma unroll
        for (int r = ty; r < 64; r += 4) {
            float v = tl[tx][r];                       // Mi[i0+tx][d0+r]
            unsigned short h = bf16_rn(v);
            unsigned short lo = bf16_rn(v - bf2f(h));
            unsigned short* row = Mbig + (size_t)(d0 + r) * GK2 + i0 + tx;
            row[0] = h; row[DM] = lo;
        }
    } else if (bid < 912) {
        int idx8 = (bid - 144) * 256 + t;              // 8 elems per thread
        int s = idx8 / (DM / 8), i0 = (idx8 % (DM / 8)) * 8;
        const float* xp = x + (size_t)s * DM + i0;
        float4 v0 = *(const float4*)xp;
        float4 v1 = *(const float4*)(xp + 4);
        float av[8] = {v0.x, v0.y, v0.z, v0.w, v1.x, v1.y, v1.z, v1.w};
        short8 hh;
#pragma unroll
        for (int q = 0; q < 8; ++q) hh[q] = (short)bf16_rn(av[q]);
        *(short8*)(Xbig + (size_t)s * DM + i0) = hh;
    } else if (bid < 1212) {
        int tid = (bid - 912) * 256 + t;
        if (tid < ST * DM) {
            int d = tid / ST, j = tid % ST;
            float s = 0.f;
#pragma unroll
            for (int k = 0; k < KF; ++k)
                s += (C[j * 2 * KF + k] + C[j * 2 * KF + KF + k]) * Mf[k * DM + d];
            WpT[tid] = s;
        }
        if (tid < DM) {
            float s = 0.f;
#pragma unroll
            for (int k = 0; k < KF; ++k)
                s += (Dv[k] + Dv[KF + k]) * Mf[k * DM + tid];
            evec[tid] = s;
        }
    } else {
        if (t < ST) {
            float a = Av[t];
            float p = 1.f;
            for (int dlt = 0; dlt <= 64; ++dlt) { Apow[dlt * ST + t] = p; p *= a; }
        }
    }
}

// ---------------------------------------------------------------------------
// tables: Kmat[delta][d] = sum_j B_j A_j^delta WpT[d][j]  (64x768 fp32)
//         Ehi/Elo[t][j]  = split(A_j^(t+1))               (64x128 bf16)
//         Qhi/Qlo[j][i]  = split(B_j A_j^(63-i))          (112x64 bf16)
// ---------------------------------------------------------------------------
__global__ __launch_bounds__(256) void tables(const float* __restrict__ Bv,
                                              const float* __restrict__ Apow,
                                              const float* __restrict__ WpT,
                                              float* __restrict__ Kmat,
                                              unsigned short* __restrict__ Ehi,
                                              unsigned short* __restrict__ Elo,
                                              unsigned short* __restrict__ Qhi,
                                              unsigned short* __restrict__ Qlo) {
    int tid = blockIdx.x * 256 + threadIdx.x;
    if (tid < 64 * DM) {
        int dlt = tid / DM, d = tid % DM;
        float s = 0.f;
        for (int j = 0; j < ST; ++j)
            s += Bv[j] * Apow[dlt * ST + j] * WpT[d * ST + j];
        Kmat[dlt * DM + d] = s;
    } else if (tid < 64 * DM + 64 * KJ) {
        int r = tid - 64 * DM;
        int tt = r >> 7, j = r & 127;
        float v = (j < ST) ? Apow[(tt + 1) * ST + j] : 0.f;
        unsigned short h = bf16_rn(v);
        unsigned short lo = bf16_rn(v - bf2f(h));
        Ehi[tt * KJ + j] = h;
        Elo[tt * KJ + j] = lo;
    } else {
        int r = tid - 64 * DM - 64 * KJ;
        if (r < NJ * 64) {
            int j = r >> 6, i = r & 63;
            float v = (j < ST) ? Bv[j] * Apow[(63 - i) * ST + j] : 0.f;
            unsigned short h = bf16_rn(v);
            unsigned short lo = bf16_rn(v - bf2f(h));
            Qhi[j * 64 + i] = h;
            Qlo[j * 64 + i] = lo;
        }
    }
}

// ---------------------------------------------------------------------------
// MFMA GEMM, no atomics: 64x64 tiles (384) x KSPLIT=2 -> 768 blocks.
// Block (tile, ks) computes ut_part[ks][d][s] over K-half ks (Mh or Ml),
// plain stores into separate partial buffers (ut0 / ut1). BK=32, swizzled
// LDS, async16 staging. Consumers sum the two partials.
// ---------------------------------------------------------------------------
__global__ __launch_bounds__(256) void gemm_mfma(const unsigned short* __restrict__ Mbig,
                                                 const unsigned short* __restrict__ Xbig,
                                                 float* __restrict__ ut0,
                                                 float* __restrict__ ut1) {
    __shared__ unsigned short As[64 * 32];
    __shared__ unsigned short Bs[64 * 32];
    int t = threadIdx.x;
    int tile = blockIdx.x;
    int d0 = (tile % (DM / 64)) * 64;
    int s0 = (tile / (DM / 64)) * 64;
    int ks = blockIdx.y;
    int kb0 = ks * DM;                    // column base in Mbig: Mh | Ml
    float* utp = ks ? ut1 : ut0;
    int wave = t >> 6, lane = t & 63;
    int m16 = lane & 15, quad = lane >> 4;
    int r0 = t >> 2, q0 = ((t & 3) - (t >> 3)) & 3;   // swizzled staging slot
    float4v acc[4];
#pragma unroll
    for (int nt = 0; nt < 4; ++nt) acc[nt] = (float4v){0.f, 0.f, 0.f, 0.f};
    for (int k0 = 0; k0 < DM; k0 += 32) {
        __syncthreads();
        async16(&Mbig[(size_t)(d0 + r0) * GK2 + kb0 + k0 + q0 * 8], &As[(size_t)t * 8]);
        async16(&Xbig[(size_t)(s0 + r0) * DM + k0 + q0 * 8], &Bs[(size_t)t * 8]);
        __syncthreads();
        int arow = wave * 16 + m16;
        int aqp = (quad + (arow >> 1)) & 3;
        short8 af = *(short8*)&As[arow * 32 + aqp * 8];
        short8 bf[4];
#pragma unroll
        for (int nt = 0; nt < 4; ++nt) {
            int brow = nt * 16 + m16;
            int bqp = (quad + (brow >> 1)) & 3;
            bf[nt] = *(short8*)&Bs[brow * 32 + bqp * 8];
        }
#pragma unroll
        for (int nt = 0; nt < 4; ++nt)
            acc[nt] = __builtin_amdgcn_mfma_f32_16x16x32_bf16(af, bf[nt], acc[nt], 0, 0, 0);
    }
#pragma unroll
    for (int nt = 0; nt < 4; ++nt) {
        int dd = d0 + wave * 16 + quad * 4;
        int ss = s0 + nt * 16 + m16;
#pragma unroll
        for (int i = 0; i < 4; ++i)
            utp[(size_t)(dd + i) * SEQ + ss] = acc[nt][i];
    }
}

// ---------------------------------------------------------------------------
// hscanG: hloc GEMM ((ut0+ut1) rows x Q) + 32-step chunk scan + G write.
// ---------------------------------------------------------------------------
__global__ __launch_bounds__(256) void hscanG(const float* __restrict__ ut0,
                                              const float* __restrict__ ut1,
                                              const unsigned short* __restrict__ Qhi,
                                              const unsigned short* __restrict__ Qlo,
                                              const float* __restrict__ WpT,
                                              const float* __restrict__ Apow,
                                              unsigned short* __restrict__ Ghi,
                                              unsigned short* __restrict__ Glo) {
    __shared__ float hl[64][120];
    int m0 = blockIdx.x * 64;
    int wave = threadIdx.x >> 6, lane = threadIdx.x & 63;
    int m16 = lane & 15, quad = lane >> 4;
    float4v acc[7];
#pragma unroll
    for (int nt = 0; nt < 7; ++nt) acc[nt] = (float4v){0.f, 0.f, 0.f, 0.f};
#pragma unroll
    for (int ks = 0; ks < 2; ++ks) {
        size_t ao = (size_t)(m0 + wave * 16 + m16) * 64 + ks * 32 + quad * 8;
        float4 a0 = *(const float4*)(ut0 + ao);
        float4 a1 = *(const float4*)(ut0 + ao + 4);
        float4 b0 = *(const float4*)(ut1 + ao);
        float4 b1 = *(const float4*)(ut1 + ao + 4);
        float av[8] = {a0.x + b0.x, a0.y + b0.y, a0.z + b0.z, a0.w + b0.w,
                       a1.x + b1.x, a1.y + b1.y, a1.z + b1.z, a1.w + b1.w};
        short8 ah, al;
#pragma unroll
        for (int q = 0; q < 8; ++q) {
            unsigned short h = bf16_rn(av[q]);
            ah[q] = (short)h;
            al[q] = (short)bf16_rn(av[q] - bf2f(h));
        }
#pragma unroll
        for (int nt = 0; nt < 7; ++nt) {
            int qoff = (nt * 16 + m16) * 64 + ks * 32 + quad * 8;
            short8 bh = *(const short8*)(Qhi + qoff);
            short8 bl = *(const short8*)(Qlo + qoff);
            acc[nt] = __builtin_amdgcn_mfma_f32_16x16x32_bf16(ah, bh, acc[nt], 0, 0, 0);
            acc[nt] = __builtin_amdgcn_mfma_f32_16x16x32_bf16(ah, bl, acc[nt], 0, 0, 0);
            acc[nt] = __builtin_amdgcn_mfma_f32_16x16x32_bf16(al, bh, acc[nt], 0, 0, 0);
        }
    }
#pragma unroll
    for (int nt = 0; nt < 7; ++nt)
#pragma unroll
        for (int i = 0; i < 4; ++i)
            hl[wave * 16 + quad * 4 + i][nt * 16 + m16] = acc[nt][i];
    __syncthreads();

    int j = threadIdx.x & 127, dloc = threadIdx.x >> 7;
    int d = blockIdx.x * 2 + dloc;
    bool ja = (j < ST);
    float a64 = ja ? Apow[64 * ST + j] : 0.f;
    float w   = ja ? WpT[d * ST + j] : 0.f;
    float hs = 0.f;
    for (int c = 0; c < NC; ++c) {
        float g = ja ? (w * hs) : 0.f;
        unsigned short gh = bf16_rn(g);
        unsigned short gl = bf16_rn(g - bf2f(gh));
        size_t go = ((size_t)c * DM + d) * KJ + j;
        Ghi[go] = gh;
        Glo[go] = gl;
        float add = ja ? hl[dloc * 32 + c][j] : 0.f;
        hs = fmaf(a64, hs, add);
    }
}

// ---------------------------------------------------------------------------
// intra: register-resident causal Toeplitz per (d, chunk) + feedthrough.
// u = ut0 + uy (partial sum); result written IN PLACE into uy (the ut1
// buffer doubles as yintra — same pointer for read and write, so ordering
// is preserved; each thread only touches its own 64-float span).
// ---------------------------------------------------------------------------
__global__ __launch_bounds__(64) void intra(const float* __restrict__ ut0,
                                            float* uy,
                                            const float* __restrict__ Kmat,
                                            const float* __restrict__ evec) {
    int lane = threadIdx.x;
    int d = blockIdx.x * 2 + (lane >> 5);
    int c = lane & 31;
    size_t off = (size_t)d * SEQ + c * 64;
    float uu[64];
#pragma unroll
    for (int q = 0; q < 16; ++q) {
        float4 v0 = *(const float4*)(ut0 + off + q * 4);
        float4 v1 = *(const float4*)(uy + off + q * 4);
        uu[q * 4 + 0] = v0.x + v1.x; uu[q * 4 + 1] = v0.y + v1.y;
        uu[q * 4 + 2] = v0.z + v1.z; uu[q * 4 + 3] = v0.w + v1.w;
    }
    float e = evec[d];
    float y[64];
#pragma unroll
    for (int t = 0; t < 64; ++t) y[t] = e * uu[t];
#pragma unroll
    for (int dlt = 0; dlt < 64; ++dlt) {
        float k = Kmat[dlt * DM + d];
#pragma unroll
        for (int t = dlt; t < 64; ++t)
            y[t] = fmaf(k, uu[t - dlt], y[t]);
    }
#pragma unroll
    for (int q = 0; q < 16; ++q) {
        float4 v = make_float4(y[q * 4 + 0], y[q * 4 + 1], y[q * 4 + 2], y[q * 4 + 3]);
        *(float4*)(uy + off + q * 4) = v;
    }
}

// ---------------------------------------------------------------------------
// inter: out[c*64+t][d] = (E @ G_c)[t][d] + yintra[d][c*64+t]
// ---------------------------------------------------------------------------
__global__ __launch_bounds__(256) void inter(const unsigned short* __restrict__ Ehi,
                                             const unsigned short* __restrict__ Elo,
                                             const unsigned short* __restrict__ Ghi,
                                             const unsigned short* __restrict__ Glo,
                                             const float* __restrict__ yintra,
                                             float* __restrict__ out) {
    __shared__ float yl[64][129];
    int c = blockIdx.x;
    int d0 = blockIdx.y * 128;
    int wave = threadIdx.x >> 6, lane = threadIdx.x & 63;
    int wn = wave * 32;
    int m16 = lane & 15, quad = lane >> 4;
#pragma unroll
    for (int it = 0; it < 8; ++it) {
        int idx = threadIdx.x + it * 256;
        int row = idx >> 4, col4 = (idx & 15) * 4;
        float4 v = *(const float4*)&yintra[(size_t)(d0 + row) * SEQ + c * 64 + col4];
        yl[col4 + 0][row] = v.x;
        yl[col4 + 1][row] = v.y;
        yl[col4 + 2][row] = v.z;
        yl[col4 + 3][row] = v.w;
    }
    float4v acc[4][2];
#pragma unroll
    for (int mt = 0; mt < 4; ++mt)
#pragma unroll
        for (int nt = 0; nt < 2; ++nt) acc[mt][nt] = (float4v){0.f, 0.f, 0.f, 0.f};
#pragma unroll
    for (int ks = 0; ks < 4; ++ks) {
        short8 bh[2], bl[2];
#pragma unroll
        for (int nt = 0; nt < 2; ++nt) {
            size_t ga = ((size_t)c * DM + d0 + wn + nt * 16 + m16) * KJ + ks * 32 + quad * 8;
            bh[nt] = *(const short8*)(Ghi + ga);
            bl[nt] = *(const short8*)(Glo + ga);
        }
#pragma unroll
        for (int mt = 0; mt < 4; ++mt) {
            int eo = (mt * 16 + m16) * KJ + ks * 32 + quad * 8;
            short8 ah = *(const short8*)(Ehi + eo);
            short8 al = *(const short8*)(Elo + eo);
#pragma unroll
            for (int nt = 0; nt < 2; ++nt) {
                acc[mt][nt] = __builtin_amdgcn_mfma_f32_16x16x32_bf16(ah, bh[nt], acc[mt][nt], 0, 0, 0);
                acc[mt][nt] = __builtin_amdgcn_mfma_f32_16x16x32_bf16(ah, bl[nt], acc[mt][nt], 0, 0, 0);
                acc[mt][nt] = __builtin_amdgcn_mfma_f32_16x16x32_bf16(al, bh[nt], acc[mt][nt], 0, 0, 0);
            }
        }
    }
    __syncthreads();
#pragma unroll
    for (int mt = 0; mt < 4; ++mt)
#pragma unroll
        for (int nt = 0; nt < 2; ++nt) {
            int tt = mt * 16 + quad * 4;
            int dcol = wn + nt * 16 + m16;
#pragma unroll
            for (int i = 0; i < 4; ++i) {
                float v = acc[mt][nt][i] + yl[tt + i][dcol];
                out[(size_t)(c * 64 + tt + i) * DM + d0 + dcol] = v;
            }
        }
}

extern "C" void kernel_launch(void* const* d_in, const int* in_sizes, int n_in,
                              void* d_out, int out_size, void* d_ws, size_t ws_size,
                              hipStream_t stream) {
    const float* x  = (const float*)d_in[0];
    const float* Mi = (const float*)d_in[2];
    const float* Mf = (const float*)d_in[3];
    const float* Av = (const float*)d_in[4];
    const float* Bv = (const float*)d_in[5];
    const float* C  = (const float*)d_in[6];
    const float* Dv = (const float*)d_in[7];
    float* out = (float*)d_out;

    float* ut0    = (float*)d_ws;                         // 768*2048
    float* WpT    = ut0 + (size_t)DM * SEQ;               // 768*100
    float* ev     = WpT + DM * ST;                        // 768
    float* Apow   = ev + DM;                              // 65*100
    float* Kmat   = Apow + 65 * ST;                       // 64*768
    float* ut1    = Kmat + 64 * DM;                       // 768*2048 (also yintra)
    unsigned short* Mbig = (unsigned short*)(ut1 + (size_t)DM * SEQ);   // 768*1536
    unsigned short* Xbig = Mbig + (size_t)DM * GK2;       // 2048*768
    unsigned short* Ehi  = Xbig + (size_t)SEQ * DM;       // 64*128
    unsigned short* Elo  = Ehi + 64 * KJ;
    unsigned short* Qhi  = Elo + 64 * KJ;                 // 112*64
    unsigned short* Qlo  = Qhi + NJ * 64;
    unsigned short* Ghi  = Qlo + NJ * 64;                 // 32*768*128
    unsigned short* Glo  = Ghi + (size_t)NC * DM * KJ;

    prep<<<1213, 256, 0, stream>>>(x, Mi, C, Dv, Mf, Av, Mbig, Xbig, WpT, ev, Apow);
    tables<<<252, 256, 0, stream>>>(Bv, Apow, WpT, Kmat, Ehi, Elo, Qhi, Qlo);
    gemm_mfma<<<dim3((DM / 64) * (SEQ / 64), 2), 256, 0, stream>>>(Mbig, Xbig, ut0, ut1);
    hscanG<<<384, 256, 0, stream>>>(ut0, ut1, Qhi, Qlo, WpT, Apow, Ghi, Glo);
    intra<<<384, 64, 0, stream>>>(ut0, ut1, Kmat, ev);
    inter<<<dim3(NC, DM / 128), 256, 0, stream>>>(Ehi, Elo, Ghi, Glo, ut1, out);
}

// Round 9
// 137.352 us; speedup vs baseline: 3.2253x; 1.0096x over previous
//
#include <hip/hip_runtime.h>

#define SEQ   2048
#define DM    768
#define ST    100
#define KF    24
#define NC    32      // SEQ / 64
#define KJ    128     // padded state dim (inter-GEMM K)
#define NJ    112     // padded state dim (hloc-GEMM N)
#define GK2   1536    // 2 * DM  (bf16x2 split K for input GEMM)

using short8  = __attribute__((ext_vector_type(8))) short;
using float4v = __attribute__((ext_vector_type(4))) float;

__device__ __forceinline__ unsigned short bf16_rn(float x) {
    unsigned int u = __float_as_uint(x);
    unsigned int r = u + 0x7FFFu + ((u >> 16) & 1u);
    return (unsigned short)(r >> 16);
}
__device__ __forceinline__ float bf2f(unsigned short h) {
    return __uint_as_float(((unsigned int)h) << 16);
}
__device__ __forceinline__ void async16(const void* g, void* l) {
    __builtin_amdgcn_global_load_lds(
        (const __attribute__((address_space(1))) unsigned int*)g,
        (__attribute__((address_space(3))) unsigned int*)l, 16, 0, 0);
}

// ---------------------------------------------------------------------------
// prep: block ranges:
//  [0,144)      Mbig[d][k] = [Mh^T | Ml^T]
//  [144,912)    Xbig[s][i] = bf16(x)           (16B stores)
//  [912,1212)   WpT[d][j] = sum_k (C[j,k]+C[j,k+24])*Mf[k,d];  ev[d]
//  [1212]       Apow[dlt][j]=A^dlt (dlt 0..64); Ehi/Elo[t][j]=split(A^(t+1));
//               Qhi/Qlo[j][i]=split(B_j A^(63-i))   (all incremental powers)
// ---------------------------------------------------------------------------
__global__ __launch_bounds__(256) void prep(const float* __restrict__ x,
                                            const float* __restrict__ Mi,
                                            const float* __restrict__ C,
                                            const float* __restrict__ Dv,
                                            const float* __restrict__ Mf,
                                            const float* __restrict__ Av,
                                            const float* __restrict__ Bv,
                                            unsigned short* __restrict__ Mbig,
                                            unsigned short* __restrict__ Xbig,
                                            float* __restrict__ WpT,
                                            float* __restrict__ evec,
                                            float* __restrict__ Apow,
                                            unsigned short* __restrict__ Ehi,
                                            unsigned short* __restrict__ Elo,
                                            unsigned short* __restrict__ Qhi,
                                            unsigned short* __restrict__ Qlo) {
    __shared__ float tl[64][65];
    int bid = blockIdx.x, t = threadIdx.x;
    if (bid < 144) {
        int i0 = (bid / 12) * 64, d0 = (bid % 12) * 64;
        int tx = t & 63, ty = t >> 6;
#pragma unroll
        for (int r = ty; r < 64; r += 4)
            tl[r][tx] = Mi[(i0 + r) * DM + d0 + tx];
        __syncthreads();
#pragma unroll
        for (int r = ty; r < 64; r += 4) {
            float v = tl[tx][r];                       // Mi[i0+tx][d0+r]
            unsigned short h = bf16_rn(v);
            unsigned short lo = bf16_rn(v - bf2f(h));
            unsigned short* row = Mbig + (size_t)(d0 + r) * GK2 + i0 + tx;
            row[0] = h; row[DM] = lo;
        }
    } else if (bid < 912) {
        int idx8 = (bid - 144) * 256 + t;              // 8 elems per thread
        int s = idx8 / (DM / 8), i0 = (idx8 % (DM / 8)) * 8;
        const float* xp = x + (size_t)s * DM + i0;
        float4 v0 = *(const float4*)xp;
        float4 v1 = *(const float4*)(xp + 4);
        float av[8] = {v0.x, v0.y, v0.z, v0.w, v1.x, v1.y, v1.z, v1.w};
        short8 hh;
#pragma unroll
        for (int q = 0; q < 8; ++q) hh[q] = (short)bf16_rn(av[q]);
        *(short8*)(Xbig + (size_t)s * DM + i0) = hh;
    } else if (bid < 1212) {
        int tid = (bid - 912) * 256 + t;
        if (tid < ST * DM) {
            int d = tid / ST, j = tid % ST;
            float s = 0.f;
#pragma unroll
            for (int k = 0; k < KF; ++k)
                s += (C[j * 2 * KF + k] + C[j * 2 * KF + KF + k]) * Mf[k * DM + d];
            WpT[tid] = s;
        }
        if (tid < DM) {
            float s = 0.f;
#pragma unroll
            for (int k = 0; k < KF; ++k)
                s += (Dv[k] + Dv[KF + k]) * Mf[k * DM + tid];
            evec[tid] = s;
        }
    } else {
        if (t < KJ) {
            bool ja = (t < ST);
            float a = ja ? Av[t] : 0.f;
            float b = ja ? Bv[t] : 0.f;
            float p = 1.f;                             // p = A^dlt
            for (int dlt = 0; dlt < 64; ++dlt) {
                if (ja) Apow[dlt * ST + t] = p;
                if (t < NJ) {                          // Q[j][63-dlt] = B*A^dlt
                    float v = b * p;
                    unsigned short h = bf16_rn(v);
                    Qhi[t * 64 + 63 - dlt] = h;
                    Qlo[t * 64 + 63 - dlt] = bf16_rn(v - bf2f(h));
                }
                p *= a;                                // p = A^(dlt+1)
                unsigned short h = bf16_rn(p);         // E[dlt][j] = A^(dlt+1)
                Ehi[dlt * KJ + t] = h;
                Elo[dlt * KJ + t] = bf16_rn(p - bf2f(h));
            }
            if (ja) Apow[64 * ST + t] = p;             // A^64
        }
    }
}

// ---------------------------------------------------------------------------
// MFMA GEMM, no atomics: 64x64 tiles (384) x KSPLIT=2 -> 768 blocks.
// Block (tile, ks) computes ut_part[ks] over K-half ks (Mh or Ml), plain
// stores into ut0 / ut1. BK=32, swizzled LDS, async16 staging. (R8 exact)
// ---------------------------------------------------------------------------
__global__ __launch_bounds__(256) void gemm_mfma(const unsigned short* __restrict__ Mbig,
                                                 const unsigned short* __restrict__ Xbig,
                                                 float* __restrict__ ut0,
                                                 float* __restrict__ ut1) {
    __shared__ unsigned short As[64 * 32];
    __shared__ unsigned short Bs[64 * 32];
    int t = threadIdx.x;
    int tile = blockIdx.x;
    int d0 = (tile % (DM / 64)) * 64;
    int s0 = (tile / (DM / 64)) * 64;
    int ks = blockIdx.y;
    int kb0 = ks * DM;
    float* utp = ks ? ut1 : ut0;
    int wave = t >> 6, lane = t & 63;
    int m16 = lane & 15, quad = lane >> 4;
    int r0 = t >> 2, q0 = ((t & 3) - (t >> 3)) & 3;
    float4v acc[4];
#pragma unroll
    for (int nt = 0; nt < 4; ++nt) acc[nt] = (float4v){0.f, 0.f, 0.f, 0.f};
    for (int k0 = 0; k0 < DM; k0 += 32) {
        __syncthreads();
        async16(&Mbig[(size_t)(d0 + r0) * GK2 + kb0 + k0 + q0 * 8], &As[(size_t)t * 8]);
        async16(&Xbig[(size_t)(s0 + r0) * DM + k0 + q0 * 8], &Bs[(size_t)t * 8]);
        __syncthreads();
        int arow = wave * 16 + m16;
        int aqp = (quad + (arow >> 1)) & 3;
        short8 af = *(short8*)&As[arow * 32 + aqp * 8];
        short8 bf[4];
#pragma unroll
        for (int nt = 0; nt < 4; ++nt) {
            int brow = nt * 16 + m16;
            int bqp = (quad + (brow >> 1)) & 3;
            bf[nt] = *(short8*)&Bs[brow * 32 + bqp * 8];
        }
#pragma unroll
        for (int nt = 0; nt < 4; ++nt)
            acc[nt] = __builtin_amdgcn_mfma_f32_16x16x32_bf16(af, bf[nt], acc[nt], 0, 0, 0);
    }
#pragma unroll
    for (int nt = 0; nt < 4; ++nt) {
        int dd = d0 + wave * 16 + quad * 4;
        int ss = s0 + nt * 16 + m16;
#pragma unroll
        for (int i = 0; i < 4; ++i)
            utp[(size_t)(dd + i) * SEQ + ss] = acc[nt][i];
    }
}

// ---------------------------------------------------------------------------
// scanf_k: fused Kmat + hloc GEMM + chunk scan + G write + intra Toeplitz.
// Block = 2 channels (384 blocks, 256 threads).
//  P0 (t<128): kk[dloc*64+dlt] = sum_j Bv[j] Apow[dlt][j] WpT[d][j]  -> LDS
//  P1 (all):   hloc = (ut0+ut1) rows @ Q^T (MFMA)                    -> hl LDS
//  P2 (all):   32-step inter-chunk scan -> Ghi/Glo
//  P3 (t<64):  register Toeplitz, y -> ut1 in place (R8 intra verbatim)
// ---------------------------------------------------------------------------
__global__ __launch_bounds__(256) void scanf_k(const float* __restrict__ ut0,
                                               float* uy,
                                               const unsigned short* __restrict__ Qhi,
                                               const unsigned short* __restrict__ Qlo,
                                               const float* __restrict__ WpT,
                                               const float* __restrict__ Apow,
                                               const float* __restrict__ Bv,
                                               const float* __restrict__ evec,
                                               unsigned short* __restrict__ Ghi,
                                               unsigned short* __restrict__ Glo) {
    __shared__ float hl[64][120];
    __shared__ float kk[128];
    int t = threadIdx.x;
    int m0 = blockIdx.x * 64;
    int d0 = blockIdx.x * 2;
    // ---- P0: Kmat taps for this block's 2 channels ----
    if (t < 128) {
        int dlt = t & 63, dloc = t >> 6;
        const float* wrow = WpT + (d0 + dloc) * ST;
        float s = 0.f;
        for (int j = 0; j < ST; ++j)
            s = fmaf(Bv[j] * Apow[dlt * ST + j], wrow[j], s);
        kk[t] = s;
    }
    // ---- P1: hloc MFMA ----
    int wave = t >> 6, lane = t & 63;
    int m16 = lane & 15, quad = lane >> 4;
    {
        float4v acc[7];
#pragma unroll
        for (int nt = 0; nt < 7; ++nt) acc[nt] = (float4v){0.f, 0.f, 0.f, 0.f};
#pragma unroll
        for (int ks = 0; ks < 2; ++ks) {
            size_t ao = (size_t)(m0 + wave * 16 + m16) * 64 + ks * 32 + quad * 8;
            float4 a0 = *(const float4*)(ut0 + ao);
            float4 a1 = *(const float4*)(ut0 + ao + 4);
            float4 b0 = *(const float4*)(uy + ao);
            float4 b1 = *(const float4*)(uy + ao + 4);
            float av[8] = {a0.x + b0.x, a0.y + b0.y, a0.z + b0.z, a0.w + b0.w,
                           a1.x + b1.x, a1.y + b1.y, a1.z + b1.z, a1.w + b1.w};
            short8 ah, al;
#pragma unroll
            for (int q = 0; q < 8; ++q) {
                unsigned short h = bf16_rn(av[q]);
                ah[q] = (short)h;
                al[q] = (short)bf16_rn(av[q] - bf2f(h));
            }
#pragma unroll
            for (int nt = 0; nt < 7; ++nt) {
                int qoff = (nt * 16 + m16) * 64 + ks * 32 + quad * 8;
                short8 bh = *(const short8*)(Qhi + qoff);
                short8 bl = *(const short8*)(Qlo + qoff);
                acc[nt] = __builtin_amdgcn_mfma_f32_16x16x32_bf16(ah, bh, acc[nt], 0, 0, 0);
                acc[nt] = __builtin_amdgcn_mfma_f32_16x16x32_bf16(ah, bl, acc[nt], 0, 0, 0);
                acc[nt] = __builtin_amdgcn_mfma_f32_16x16x32_bf16(al, bh, acc[nt], 0, 0, 0);
            }
        }
#pragma unroll
        for (int nt = 0; nt < 7; ++nt)
#pragma unroll
            for (int i = 0; i < 4; ++i)
                hl[wave * 16 + quad * 4 + i][nt * 16 + m16] = acc[nt][i];
    }
    __syncthreads();
    // ---- P2: inter-chunk scan + G ----
    {
        int j = t & 127, dloc = t >> 7;
        int d = d0 + dloc;
        bool ja = (j < ST);
        float a64 = ja ? Apow[64 * ST + j] : 0.f;
        float w   = ja ? WpT[d * ST + j] : 0.f;
        float hs = 0.f;
        for (int c = 0; c < NC; ++c) {
            float g = ja ? (w * hs) : 0.f;
            unsigned short gh = bf16_rn(g);
            unsigned short gl = bf16_rn(g - bf2f(gh));
            size_t go = ((size_t)c * DM + d) * KJ + j;
            Ghi[go] = gh;
            Glo[go] = gl;
            float add = ja ? hl[dloc * 32 + c][j] : 0.f;
            hs = fmaf(a64, hs, add);
        }
    }
    // ---- P3: intra Toeplitz (wave 0), in-place into uy ----
    if (t < 64) {
        int dloc = t >> 5, c = t & 31;
        int d = d0 + dloc;
        size_t off = (size_t)d * SEQ + c * 64;
        float uu[64];
#pragma unroll
        for (int q = 0; q < 16; ++q) {
            float4 v0 = *(const float4*)(ut0 + off + q * 4);
            float4 v1 = *(const float4*)(uy + off + q * 4);
            uu[q * 4 + 0] = v0.x + v1.x; uu[q * 4 + 1] = v0.y + v1.y;
            uu[q * 4 + 2] = v0.z + v1.z; uu[q * 4 + 3] = v0.w + v1.w;
        }
        float e = evec[d];
        float y[64];
#pragma unroll
        for (int tt = 0; tt < 64; ++tt) y[tt] = e * uu[tt];
        const float* kt = &kk[dloc * 64];
#pragma unroll
        for (int dlt = 0; dlt < 64; ++dlt) {
            float k = kt[dlt];
#pragma unroll
            for (int tt = dlt; tt < 64; ++tt)
                y[tt] = fmaf(k, uu[tt - dlt], y[tt]);
        }
#pragma unroll
        for (int q = 0; q < 16; ++q) {
            float4 v = make_float4(y[q * 4 + 0], y[q * 4 + 1], y[q * 4 + 2], y[q * 4 + 3]);
            *(float4*)(uy + off + q * 4) = v;
        }
    }
}

// ---------------------------------------------------------------------------
// inter: out[c*64+t][d] = (E @ G_c)[t][d] + yintra[d][c*64+t]
// Block = (chunk c, 64-wide d tile): M=64, N=64, K=128, 4 waves. 384 blocks.
// ---------------------------------------------------------------------------
__global__ __launch_bounds__(256) void inter(const unsigned short* __restrict__ Ehi,
                                             const unsigned short* __restrict__ Elo,
                                             const unsigned short* __restrict__ Ghi,
                                             const unsigned short* __restrict__ Glo,
                                             const float* __restrict__ yintra,
                                             float* __restrict__ out) {
    __shared__ float yl[64][68];
    int c = blockIdx.x;
    int d0 = blockIdx.y * 64;
    int t = threadIdx.x;
#pragma unroll
    for (int it = 0; it < 4; ++it) {
        int idx = t + it * 256;
        int row = idx >> 4, col4 = (idx & 15) * 4;
        float4 v = *(const float4*)&yintra[(size_t)(d0 + row) * SEQ + c * 64 + col4];
        yl[col4 + 0][row] = v.x;
        yl[col4 + 1][row] = v.y;
        yl[col4 + 2][row] = v.z;
        yl[col4 + 3][row] = v.w;
    }
    __syncthreads();
    int wave = t >> 6, lane = t & 63;
    int wn = wave * 16;
    int m16 = lane & 15, quad = lane >> 4;
    float4v acc[4];
#pragma unroll
    for (int mt = 0; mt < 4; ++mt) acc[mt] = (float4v){0.f, 0.f, 0.f, 0.f};
#pragma unroll
    for (int ks = 0; ks < 4; ++ks) {
        size_t gb = ((size_t)c * DM + d0 + wn + m16) * KJ + ks * 32 + quad * 8;
        short8 bh = *(const short8*)(Ghi + gb);
        short8 bl = *(const short8*)(Glo + gb);
#pragma unroll
        for (int mt = 0; mt < 4; ++mt) {
            int eo = (mt * 16 + m16) * KJ + ks * 32 + quad * 8;
            short8 ah = *(const short8*)(Ehi + eo);
            short8 al = *(const short8*)(Elo + eo);
            acc[mt] = __builtin_amdgcn_mfma_f32_16x16x32_bf16(ah, bh, acc[mt], 0, 0, 0);
            acc[mt] = __builtin_amdgcn_mfma_f32_16x16x32_bf16(ah, bl, acc[mt], 0, 0, 0);
            acc[mt] = __builtin_amdgcn_mfma_f32_16x16x32_bf16(al, bh, acc[mt], 0, 0, 0);
        }
    }
#pragma unroll
    for (int mt = 0; mt < 4; ++mt) {
        int tt = mt * 16 + quad * 4;
        int dcol = wn + m16;
#pragma unroll
        for (int i = 0; i < 4; ++i) {
            float v = acc[mt][i] + yl[tt + i][dcol];
            out[(size_t)(c * 64 + tt + i) * DM + d0 + dcol] = v;
        }
    }
}

extern "C" void kernel_launch(void* const* d_in, const int* in_sizes, int n_in,
                              void* d_out, int out_size, void* d_ws, size_t ws_size,
                              hipStream_t stream) {
    const float* x  = (const float*)d_in[0];
    const float* Mi = (const float*)d_in[2];
    const float* Mf = (const float*)d_in[3];
    const float* Av = (const float*)d_in[4];
    const float* Bv = (const float*)d_in[5];
    const float* C  = (const float*)d_in[6];
    const float* Dv = (const float*)d_in[7];
    float* out = (float*)d_out;

    float* ut0    = (float*)d_ws;                         // 768*2048
    float* WpT    = ut0 + (size_t)DM * SEQ;               // 768*100
    float* ev     = WpT + DM * ST;                        // 768
    float* Apow   = ev + DM;                              // 65*100
    float* ut1    = Apow + 65 * ST;                       // 768*2048 (also yintra)
    unsigned short* Mbig = (unsigned short*)(ut1 + (size_t)DM * SEQ);   // 768*1536
    unsigned short* Xbig = Mbig + (size_t)DM * GK2;       // 2048*768
    unsigned short* Ehi  = Xbig + (size_t)SEQ * DM;       // 64*128
    unsigned short* Elo  = Ehi + 64 * KJ;
    unsigned short* Qhi  = Elo + 64 * KJ;                 // 112*64
    unsigned short* Qlo  = Qhi + NJ * 64;
    unsigned short* Ghi  = Qlo + NJ * 64;                 // 32*768*128
    unsigned short* Glo  = Ghi + (size_t)NC * DM * KJ;

    prep<<<1213, 256, 0, stream>>>(x, Mi, C, Dv, Mf, Av, Bv, Mbig, Xbig,
                                   WpT, ev, Apow, Ehi, Elo, Qhi, Qlo);
    gemm_mfma<<<dim3((DM / 64) * (SEQ / 64), 2), 256, 0, stream>>>(Mbig, Xbig, ut0, ut1);
    scanf_k<<<384, 256, 0, stream>>>(ut0, ut1, Qhi, Qlo, WpT, Apow, Bv, ev, Ghi, Glo);
    inter<<<dim3(NC, DM / 64), 256, 0, stream>>>(Ehi, Elo, Ghi, Glo, ut1, out);
}

// Round 10
// 114.559 us; speedup vs baseline: 3.8670x; 1.1990x over previous
//
#include <hip/hip_runtime.h>

#define SEQ   2048
#define DM    768
#define ST    100
#define KF    24
#define NC    32      // SEQ / 64
#define KJ    128     // padded state dim (inter-GEMM K)
#define NJ    112     // padded state dim (hloc-GEMM N)

using half8   = __attribute__((ext_vector_type(8))) _Float16;
using float4v = __attribute__((ext_vector_type(4))) float;
using ush8    = __attribute__((ext_vector_type(8))) short;

__device__ __forceinline__ unsigned short f2h(float v) {
    union { _Float16 h; unsigned short u; } cv;
    cv.h = (_Float16)v;
    return cv.u;
}
__device__ __forceinline__ void async16(const void* g, void* l) {
    __builtin_amdgcn_global_load_lds(
        (const __attribute__((address_space(1))) unsigned int*)g,
        (__attribute__((address_space(3))) unsigned int*)l, 16, 0, 0);
}

// ---------------------------------------------------------------------------
// prep: block ranges:
//  [0,144)      Mh[d][k] = fp16(Mi^T)          (64x64 LDS transpose)
//  [144,912)    Xh[s][i] = fp16(x)             (16B stores)
//  [912,1212)   WpT[d][j] = sum_k (C[j,k]+C[j,k+24])*Mf[k,d];  ev[d]
//  [1212]       Apow[dlt][j] (fp32, dlt 0..64); Eh[t][j]=fp16(A^(t+1));
//               Qh[j][i]=fp16(B_j A^(63-i))    (incremental powers only)
// ---------------------------------------------------------------------------
__global__ __launch_bounds__(256) void prep(const float* __restrict__ x,
                                            const float* __restrict__ Mi,
                                            const float* __restrict__ C,
                                            const float* __restrict__ Dv,
                                            const float* __restrict__ Mf,
                                            const float* __restrict__ Av,
                                            const float* __restrict__ Bv,
                                            unsigned short* __restrict__ Mh,
                                            unsigned short* __restrict__ Xh,
                                            float* __restrict__ WpT,
                                            float* __restrict__ evec,
                                            float* __restrict__ Apow,
                                            unsigned short* __restrict__ Eh,
                                            unsigned short* __restrict__ Qh) {
    __shared__ float tl[64][65];
    int bid = blockIdx.x, t = threadIdx.x;
    if (bid < 144) {
        int i0 = (bid / 12) * 64, d0 = (bid % 12) * 64;
        int tx = t & 63, ty = t >> 6;
#pragma unroll
        for (int r = ty; r < 64; r += 4)
            tl[r][tx] = Mi[(i0 + r) * DM + d0 + tx];
        __syncthreads();
#pragma unroll
        for (int r = ty; r < 64; r += 4)
            Mh[(size_t)(d0 + r) * DM + i0 + tx] = f2h(tl[tx][r]);
    } else if (bid < 912) {
        int idx8 = (bid - 144) * 256 + t;              // 8 elems per thread
        int s = idx8 / (DM / 8), i0 = (idx8 % (DM / 8)) * 8;
        const float* xp = x + (size_t)s * DM + i0;
        float4 v0 = *(const float4*)xp;
        float4 v1 = *(const float4*)(xp + 4);
        float av[8] = {v0.x, v0.y, v0.z, v0.w, v1.x, v1.y, v1.z, v1.w};
        ush8 hh;
#pragma unroll
        for (int q = 0; q < 8; ++q) hh[q] = (short)f2h(av[q]);
        *(ush8*)(Xh + (size_t)s * DM + i0) = hh;
    } else if (bid < 1212) {
        int tid = (bid - 912) * 256 + t;
        if (tid < ST * DM) {
            int d = tid / ST, j = tid % ST;
            float s = 0.f;
#pragma unroll
            for (int k = 0; k < KF; ++k)
                s += (C[j * 2 * KF + k] + C[j * 2 * KF + KF + k]) * Mf[k * DM + d];
            WpT[tid] = s;
        }
        if (tid < DM) {
            float s = 0.f;
#pragma unroll
            for (int k = 0; k < KF; ++k)
                s += (Dv[k] + Dv[KF + k]) * Mf[k * DM + tid];
            evec[tid] = s;
        }
    } else {
        if (t < KJ) {
            bool ja = (t < ST);
            float a = ja ? Av[t] : 0.f;
            float b = ja ? Bv[t] : 0.f;
            float p = 1.f;                             // p = A^dlt
            for (int dlt = 0; dlt < 64; ++dlt) {
                if (ja) Apow[dlt * ST + t] = p;
                if (t < NJ) Qh[t * 64 + 63 - dlt] = f2h(b * p);
                p *= a;                                // p = A^(dlt+1)
                Eh[dlt * KJ + t] = f2h(p);
            }
            if (ja) Apow[64 * ST + t] = p;             // A^64
        }
    }
}

// ---------------------------------------------------------------------------
// MFMA GEMM (fp16, no split, no atomics): ut[d][s] = Mh[d][:] . Xh[s][:].
// 64x64 tiles, 384 blocks, BK=64 (12 iters), rotate-swizzled LDS
// (chunk q' = (q + row) & 7), async16 staging, mfma_f32_16x16x32_f16.
// ---------------------------------------------------------------------------
__global__ __launch_bounds__(256) void gemm_mfma(const unsigned short* __restrict__ Mh,
                                                 const unsigned short* __restrict__ Xh,
                                                 float* __restrict__ ut) {
    __shared__ unsigned short As[64 * 64];
    __shared__ unsigned short Bs[64 * 64];
    int t = threadIdx.x;
    int tile = blockIdx.x;
    int d0 = (tile % (DM / 64)) * 64;
    int s0 = (tile / (DM / 64)) * 64;
    int wave = t >> 6, lane = t & 63;
    int m16 = lane & 15, quad = lane >> 4;
    // staging slot L -> (row=L>>3, q'=L&7); source chunk q=(q'-row)&7
    int r0 = t >> 3,         q0 = ((t & 7) - r0) & 7;
    int r1 = (t + 256) >> 3, q1 = (((t + 256) & 7) - r1) & 7;
    float4v acc[4];
#pragma unroll
    for (int nt = 0; nt < 4; ++nt) acc[nt] = (float4v){0.f, 0.f, 0.f, 0.f};
    for (int k0 = 0; k0 < DM; k0 += 64) {
        __syncthreads();
        async16(&Mh[(size_t)(d0 + r0) * DM + k0 + q0 * 8], &As[(size_t)t * 8]);
        async16(&Xh[(size_t)(s0 + r0) * DM + k0 + q0 * 8], &Bs[(size_t)t * 8]);
        async16(&Mh[(size_t)(d0 + r1) * DM + k0 + q1 * 8], &As[(size_t)(t + 256) * 8]);
        async16(&Xh[(size_t)(s0 + r1) * DM + k0 + q1 * 8], &Bs[(size_t)(t + 256) * 8]);
        __syncthreads();
        int arow = wave * 16 + m16;
        half8 af[2], bf[4][2];
#pragma unroll
        for (int h = 0; h < 2; ++h)
            af[h] = *(half8*)&As[arow * 64 + (((h * 4 + quad) + arow) & 7) * 8];
#pragma unroll
        for (int nt = 0; nt < 4; ++nt) {
            int brow = nt * 16 + m16;
#pragma unroll
            for (int h = 0; h < 2; ++h)
                bf[nt][h] = *(half8*)&Bs[brow * 64 + (((h * 4 + quad) + brow) & 7) * 8];
        }
#pragma unroll
        for (int h = 0; h < 2; ++h)
#pragma unroll
            for (int nt = 0; nt < 4; ++nt)
                acc[nt] = __builtin_amdgcn_mfma_f32_16x16x32_f16(af[h], bf[nt][h], acc[nt], 0, 0, 0);
    }
#pragma unroll
    for (int nt = 0; nt < 4; ++nt) {
        int dd = d0 + wave * 16 + quad * 4;
        int ss = s0 + nt * 16 + m16;
#pragma unroll
        for (int i = 0; i < 4; ++i)
            ut[(size_t)(dd + i) * SEQ + ss] = acc[nt][i];
    }
}

// ---------------------------------------------------------------------------
// scanf_k: fused Kmat + hloc GEMM + chunk scan + G write + intra Toeplitz.
// Block = 2 channels (384 blocks, 256 threads). ut read, then y written
// in place into ut (block-private rows).
// ---------------------------------------------------------------------------
__global__ __launch_bounds__(256) void scanf_k(float* ut,
                                               const unsigned short* __restrict__ Qh,
                                               const float* __restrict__ WpT,
                                               const float* __restrict__ Apow,
                                               const float* __restrict__ Bv,
                                               const float* __restrict__ evec,
                                               unsigned short* __restrict__ Gh) {
    __shared__ float hl[64][120];
    __shared__ float kk[128];
    int t = threadIdx.x;
    int m0 = blockIdx.x * 64;
    int d0 = blockIdx.x * 2;
    // ---- P0: Kmat taps for this block's 2 channels ----
    if (t < 128) {
        int dlt = t & 63, dloc = t >> 6;
        const float* wrow = WpT + (d0 + dloc) * ST;
        float s = 0.f;
        for (int j = 0; j < ST; ++j)
            s = fmaf(Bv[j] * Apow[dlt * ST + j], wrow[j], s);
        kk[t] = s;
    }
    // ---- P1: hloc = ut rows @ Q^T (fp16 MFMA) ----
    int wave = t >> 6, lane = t & 63;
    int m16 = lane & 15, quad = lane >> 4;
    {
        float4v acc[7];
#pragma unroll
        for (int nt = 0; nt < 7; ++nt) acc[nt] = (float4v){0.f, 0.f, 0.f, 0.f};
#pragma unroll
        for (int ks = 0; ks < 2; ++ks) {
            size_t ao = (size_t)(m0 + wave * 16 + m16) * 64 + ks * 32 + quad * 8;
            float4 a0 = *(const float4*)(ut + ao);
            float4 a1 = *(const float4*)(ut + ao + 4);
            float av[8] = {a0.x, a0.y, a0.z, a0.w, a1.x, a1.y, a1.z, a1.w};
            half8 ah;
#pragma unroll
            for (int q = 0; q < 8; ++q) ah[q] = (_Float16)av[q];
#pragma unroll
            for (int nt = 0; nt < 7; ++nt) {
                half8 bh = *(const half8*)(Qh + (nt * 16 + m16) * 64 + ks * 32 + quad * 8);
                acc[nt] = __builtin_amdgcn_mfma_f32_16x16x32_f16(ah, bh, acc[nt], 0, 0, 0);
            }
        }
#pragma unroll
        for (int nt = 0; nt < 7; ++nt)
#pragma unroll
            for (int i = 0; i < 4; ++i)
                hl[wave * 16 + quad * 4 + i][nt * 16 + m16] = acc[nt][i];
    }
    __syncthreads();
    // ---- P2: inter-chunk scan + G = fp16(w * hs) ----
    {
        int j = t & 127, dloc = t >> 7;
        int d = d0 + dloc;
        bool ja = (j < ST);
        float a64 = ja ? Apow[64 * ST + j] : 0.f;
        float w   = ja ? WpT[d * ST + j] : 0.f;
        float hs = 0.f;
        for (int c = 0; c < NC; ++c) {
            Gh[((size_t)c * DM + d) * KJ + j] = f2h(w * hs);
            float add = ja ? hl[dloc * 32 + c][j] : 0.f;
            hs = fmaf(a64, hs, add);
        }
    }
    // ---- P3: intra Toeplitz (wave 0), in place into ut ----
    if (t < 64) {
        int dloc = t >> 5, c = t & 31;
        int d = d0 + dloc;
        size_t off = (size_t)d * SEQ + c * 64;
        float uu[64];
#pragma unroll
        for (int q = 0; q < 16; ++q) {
            float4 v = *(const float4*)(ut + off + q * 4);
            uu[q * 4 + 0] = v.x; uu[q * 4 + 1] = v.y;
            uu[q * 4 + 2] = v.z; uu[q * 4 + 3] = v.w;
        }
        float e = evec[d];
        float y[64];
#pragma unroll
        for (int tt = 0; tt < 64; ++tt) y[tt] = e * uu[tt];
        const float* kt = &kk[dloc * 64];
#pragma unroll
        for (int dlt = 0; dlt < 64; ++dlt) {
            float k = kt[dlt];
#pragma unroll
            for (int tt = dlt; tt < 64; ++tt)
                y[tt] = fmaf(k, uu[tt - dlt], y[tt]);
        }
#pragma unroll
        for (int q = 0; q < 16; ++q) {
            float4 v = make_float4(y[q * 4 + 0], y[q * 4 + 1], y[q * 4 + 2], y[q * 4 + 3]);
            *(float4*)(ut + off + q * 4) = v;
        }
    }
}

// ---------------------------------------------------------------------------
// inter: out[c*64+t][d] = (E @ G_c)[t][d] + yintra[d][c*64+t]
// Block = (chunk c, 64-wide d tile): M=64, N=64, K=128 fp16, 4 waves.
// ---------------------------------------------------------------------------
__global__ __launch_bounds__(256) void inter(const unsigned short* __restrict__ Eh,
                                             const unsigned short* __restrict__ Gh,
                                             const float* __restrict__ yintra,
                                             float* __restrict__ out) {
    __shared__ float yl[64][68];
    int c = blockIdx.x;
    int d0 = blockIdx.y * 64;
    int t = threadIdx.x;
#pragma unroll
    for (int it = 0; it < 4; ++it) {
        int idx = t + it * 256;
        int row = idx >> 4, col4 = (idx & 15) * 4;
        float4 v = *(const float4*)&yintra[(size_t)(d0 + row) * SEQ + c * 64 + col4];
        yl[col4 + 0][row] = v.x;
        yl[col4 + 1][row] = v.y;
        yl[col4 + 2][row] = v.z;
        yl[col4 + 3][row] = v.w;
    }
    __syncthreads();
    int wave = t >> 6, lane = t & 63;
    int wn = wave * 16;
    int m16 = lane & 15, quad = lane >> 4;
    float4v acc[4];
#pragma unroll
    for (int mt = 0; mt < 4; ++mt) acc[mt] = (float4v){0.f, 0.f, 0.f, 0.f};
#pragma unroll
    for (int ks = 0; ks < 4; ++ks) {
        half8 bh = *(const half8*)(Gh + ((size_t)c * DM + d0 + wn + m16) * KJ + ks * 32 + quad * 8);
#pragma unroll
        for (int mt = 0; mt < 4; ++mt) {
            half8 ah = *(const half8*)(Eh + (mt * 16 + m16) * KJ + ks * 32 + quad * 8);
            acc[mt] = __builtin_amdgcn_mfma_f32_16x16x32_f16(ah, bh, acc[mt], 0, 0, 0);
        }
    }
#pragma unroll
    for (int mt = 0; mt < 4; ++mt) {
        int tt = mt * 16 + quad * 4;
        int dcol = wn + m16;
#pragma unroll
        for (int i = 0; i < 4; ++i) {
            float v = acc[mt][i] + yl[tt + i][dcol];
            out[(size_t)(c * 64 + tt + i) * DM + d0 + dcol] = v;
        }
    }
}

extern "C" void kernel_launch(void* const* d_in, const int* in_sizes, int n_in,
                              void* d_out, int out_size, void* d_ws, size_t ws_size,
                              hipStream_t stream) {
    const float* x  = (const float*)d_in[0];
    const float* Mi = (const float*)d_in[2];
    const float* Mf = (const float*)d_in[3];
    const float* Av = (const float*)d_in[4];
    const float* Bv = (const float*)d_in[5];
    const float* C  = (const float*)d_in[6];
    const float* Dv = (const float*)d_in[7];
    float* out = (float*)d_out;

    float* ut   = (float*)d_ws;                           // 768*2048 f32
    float* WpT  = ut + (size_t)DM * SEQ;                  // 768*100
    float* ev   = WpT + DM * ST;                          // 768
    float* Apow = ev + DM;                                // 65*100
    unsigned short* Mh = (unsigned short*)(Apow + 65 * ST);   // 768*768 fp16
    unsigned short* Xh = Mh + (size_t)DM * DM;            // 2048*768 fp16
    unsigned short* Eh = Xh + (size_t)SEQ * DM;           // 64*128 fp16
    unsigned short* Qh = Eh + 64 * KJ;                    // 112*64 fp16
    unsigned short* Gh = Qh + NJ * 64;                    // 32*768*128 fp16

    prep<<<1213, 256, 0, stream>>>(x, Mi, C, Dv, Mf, Av, Bv, Mh, Xh,
                                   WpT, ev, Apow, Eh, Qh);
    gemm_mfma<<<(DM / 64) * (SEQ / 64), 256, 0, stream>>>(Mh, Xh, ut);
    scanf_k<<<384, 256, 0, stream>>>(ut, Qh, WpT, Apow, Bv, ev, Gh);
    inter<<<dim3(NC, DM / 64), 256, 0, stream>>>(Eh, Gh, ut, out);
}

// Round 12
// 113.774 us; speedup vs baseline: 3.8937x; 1.0069x over previous
//
#include <hip/hip_runtime.h>

#define SEQ   2048
#define DM    768
#define ST    100
#define KF    24
#define NC    32      // SEQ / 64
#define KJ    128     // padded state dim (inter-GEMM K)
#define NJ    112     // padded state dim (hloc-GEMM N)

using half8   = __attribute__((ext_vector_type(8))) _Float16;
using float4v = __attribute__((ext_vector_type(4))) float;
using ush8    = __attribute__((ext_vector_type(8))) short;

__device__ __forceinline__ unsigned short f2h(float v) {
    union { _Float16 h; unsigned short u; } cv;
    cv.h = (_Float16)v;
    return cv.u;
}
__device__ __forceinline__ void async16(const void* g, void* l) {
    __builtin_amdgcn_global_load_lds(
        (const __attribute__((address_space(1))) unsigned int*)g,
        (__attribute__((address_space(3))) unsigned int*)l, 16, 0, 0);
}

// ---------------------------------------------------------------------------
// prep: block ranges:
//  [0,144)      Mh[d][k] = fp16(Mi^T)          (64x64 LDS transpose)
//  [144,912)    Xh[s][i] = fp16(x)             (16B stores)
//  [912,1212)   WpT[d][j] = sum_k (C[j,k]+C[j,k+24])*Mf[k,d];  ev[d]
//  [1212]       Apow[dlt][j] (fp32, dlt 0..64); Eh[t][j]=fp16(A^(t+1));
//               Qh[j][i]=fp16(B_j A^(63-i))    (incremental powers only)
// ---------------------------------------------------------------------------
__global__ __launch_bounds__(256) void prep(const float* __restrict__ x,
                                            const float* __restrict__ Mi,
                                            const float* __restrict__ C,
                                            const float* __restrict__ Dv,
                                            const float* __restrict__ Mf,
                                            const float* __restrict__ Av,
                                            const float* __restrict__ Bv,
                                            unsigned short* __restrict__ Mh,
                                            unsigned short* __restrict__ Xh,
                                            float* __restrict__ WpT,
                                            float* __restrict__ evec,
                                            float* __restrict__ Apow,
                                            unsigned short* __restrict__ Eh,
                                            unsigned short* __restrict__ Qh) {
    __shared__ float tl[64][65];
    int bid = blockIdx.x, t = threadIdx.x;
    if (bid < 144) {
        int i0 = (bid / 12) * 64, d0 = (bid % 12) * 64;
        int tx = t & 63, ty = t >> 6;
#pragma unroll
        for (int r = ty; r < 64; r += 4)
            tl[r][tx] = Mi[(i0 + r) * DM + d0 + tx];
        __syncthreads();
#pragma unroll
        for (int r = ty; r < 64; r += 4)
            Mh[(size_t)(d0 + r) * DM + i0 + tx] = f2h(tl[tx][r]);
    } else if (bid < 912) {
        int idx8 = (bid - 144) * 256 + t;              // 8 elems per thread
        int s = idx8 / (DM / 8), i0 = (idx8 % (DM / 8)) * 8;
        const float* xp = x + (size_t)s * DM + i0;
        float4 v0 = *(const float4*)xp;
        float4 v1 = *(const float4*)(xp + 4);
        float av[8] = {v0.x, v0.y, v0.z, v0.w, v1.x, v1.y, v1.z, v1.w};
        ush8 hh;
#pragma unroll
        for (int q = 0; q < 8; ++q) hh[q] = (short)f2h(av[q]);
        *(ush8*)(Xh + (size_t)s * DM + i0) = hh;
    } else if (bid < 1212) {
        int tid = (bid - 912) * 256 + t;
        if (tid < ST * DM) {
            int d = tid / ST, j = tid % ST;
            float s = 0.f;
#pragma unroll
            for (int k = 0; k < KF; ++k)
                s += (C[j * 2 * KF + k] + C[j * 2 * KF + KF + k]) * Mf[k * DM + d];
            WpT[tid] = s;
        }
        if (tid < DM) {
            float s = 0.f;
#pragma unroll
            for (int k = 0; k < KF; ++k)
                s += (Dv[k] + Dv[KF + k]) * Mf[k * DM + tid];
            evec[tid] = s;
        }
    } else {
        if (t < KJ) {
            bool ja = (t < ST);
            float a = ja ? Av[t] : 0.f;
            float b = ja ? Bv[t] : 0.f;
            float p = 1.f;                             // p = A^dlt
            for (int dlt = 0; dlt < 64; ++dlt) {
                if (ja) Apow[dlt * ST + t] = p;
                if (t < NJ) Qh[t * 64 + 63 - dlt] = f2h(b * p);
                p *= a;                                // p = A^(dlt+1)
                Eh[dlt * KJ + t] = f2h(p);
            }
            if (ja) Apow[64 * ST + t] = p;             // A^64
        }
    }
}

// ---------------------------------------------------------------------------
// MFMA GEMM (fp16, no split, no atomics): ut[d][s] = Mh[d][:] . Xh[s][:].
// 64x64 tiles, 384 blocks, BK=64 (12 iters), rotate-swizzled LDS
// (chunk q' = (q + row) & 7), async16 staging, mfma_f32_16x16x32_f16.
// ---------------------------------------------------------------------------
__global__ __launch_bounds__(256) void gemm_mfma(const unsigned short* __restrict__ Mh,
                                                 const unsigned short* __restrict__ Xh,
                                                 float* __restrict__ ut) {
    __shared__ unsigned short As[64 * 64];
    __shared__ unsigned short Bs[64 * 64];
    int t = threadIdx.x;
    int tile = blockIdx.x;
    int d0 = (tile % (DM / 64)) * 64;
    int s0 = (tile / (DM / 64)) * 64;
    int wave = t >> 6, lane = t & 63;
    int m16 = lane & 15, quad = lane >> 4;
    // staging slot L -> (row=L>>3, q'=L&7); source chunk q=(q'-row)&7
    int r0 = t >> 3,         q0 = ((t & 7) - r0) & 7;
    int r1 = (t + 256) >> 3, q1 = (((t + 256) & 7) - r1) & 7;
    float4v acc[4];
#pragma unroll
    for (int nt = 0; nt < 4; ++nt) acc[nt] = (float4v){0.f, 0.f, 0.f, 0.f};
    for (int k0 = 0; k0 < DM; k0 += 64) {
        __syncthreads();
        async16(&Mh[(size_t)(d0 + r0) * DM + k0 + q0 * 8], &As[(size_t)t * 8]);
        async16(&Xh[(size_t)(s0 + r0) * DM + k0 + q0 * 8], &Bs[(size_t)t * 8]);
        async16(&Mh[(size_t)(d0 + r1) * DM + k0 + q1 * 8], &As[(size_t)(t + 256) * 8]);
        async16(&Xh[(size_t)(s0 + r1) * DM + k0 + q1 * 8], &Bs[(size_t)(t + 256) * 8]);
        __syncthreads();
        int arow = wave * 16 + m16;
        half8 af[2], bf[4][2];
#pragma unroll
        for (int h = 0; h < 2; ++h)
            af[h] = *(half8*)&As[arow * 64 + (((h * 4 + quad) + arow) & 7) * 8];
#pragma unroll
        for (int nt = 0; nt < 4; ++nt) {
            int brow = nt * 16 + m16;
#pragma unroll
            for (int h = 0; h < 2; ++h)
                bf[nt][h] = *(half8*)&Bs[brow * 64 + (((h * 4 + quad) + brow) & 7) * 8];
        }
#pragma unroll
        for (int h = 0; h < 2; ++h)
#pragma unroll
            for (int nt = 0; nt < 4; ++nt)
                acc[nt] = __builtin_amdgcn_mfma_f32_16x16x32_f16(af[h], bf[nt][h], acc[nt], 0, 0, 0);
    }
#pragma unroll
    for (int nt = 0; nt < 4; ++nt) {
        int dd = d0 + wave * 16 + quad * 4;
        int ss = s0 + nt * 16 + m16;
#pragma unroll
        for (int i = 0; i < 4; ++i)
            ut[(size_t)(dd + i) * SEQ + ss] = acc[nt][i];
    }
}

// ---------------------------------------------------------------------------
// scanf_k: fused Kmat + hloc GEMM + chunk scan + G write + intra Toeplitz.
// Block = 2 channels (384 blocks, 256 threads). ut read, then y written
// in place into ut (block-private rows).
// ---------------------------------------------------------------------------
__global__ __launch_bounds__(256) void scanf_k(float* ut,
                                               const unsigned short* __restrict__ Qh,
                                               const float* __restrict__ WpT,
                                               const float* __restrict__ Apow,
                                               const float* __restrict__ Bv,
                                               const float* __restrict__ evec,
                                               unsigned short* __restrict__ Gh) {
    __shared__ float hl[64][120];
    __shared__ float kk[128];
    int t = threadIdx.x;
    int m0 = blockIdx.x * 64;
    int d0 = blockIdx.x * 2;
    // ---- P0: Kmat taps for this block's 2 channels ----
    if (t < 128) {
        int dlt = t & 63, dloc = t >> 6;
        const float* wrow = WpT + (d0 + dloc) * ST;
        float s = 0.f;
        for (int j = 0; j < ST; ++j)
            s = fmaf(Bv[j] * Apow[dlt * ST + j], wrow[j], s);
        kk[t] = s;
    }
    // ---- P1: hloc = ut rows @ Q^T (fp16 MFMA) ----
    int wave = t >> 6, lane = t & 63;
    int m16 = lane & 15, quad = lane >> 4;
    {
        float4v acc[7];
#pragma unroll
        for (int nt = 0; nt < 7; ++nt) acc[nt] = (float4v){0.f, 0.f, 0.f, 0.f};
#pragma unroll
        for (int ks = 0; ks < 2; ++ks) {
            size_t ao = (size_t)(m0 + wave * 16 + m16) * 64 + ks * 32 + quad * 8;
            float4 a0 = *(const float4*)(ut + ao);
            float4 a1 = *(const float4*)(ut + ao + 4);
            float av[8] = {a0.x, a0.y, a0.z, a0.w, a1.x, a1.y, a1.z, a1.w};
            half8 ah;
#pragma unroll
            for (int q = 0; q < 8; ++q) ah[q] = (_Float16)av[q];
#pragma unroll
            for (int nt = 0; nt < 7; ++nt) {
                half8 bh = *(const half8*)(Qh + (nt * 16 + m16) * 64 + ks * 32 + quad * 8);
                acc[nt] = __builtin_amdgcn_mfma_f32_16x16x32_f16(ah, bh, acc[nt], 0, 0, 0);
            }
        }
#pragma unroll
        for (int nt = 0; nt < 7; ++nt)
#pragma unroll
            for (int i = 0; i < 4; ++i)
                hl[wave * 16 + quad * 4 + i][nt * 16 + m16] = acc[nt][i];
    }
    __syncthreads();
    // ---- P2: inter-chunk scan + G = fp16(w * hs) ----
    {
        int j = t & 127, dloc = t >> 7;
        int d = d0 + dloc;
        bool ja = (j < ST);
        float a64 = ja ? Apow[64 * ST + j] : 0.f;
        float w   = ja ? WpT[d * ST + j] : 0.f;
        float hs = 0.f;
        for (int c = 0; c < NC; ++c) {
            Gh[((size_t)c * DM + d) * KJ + j] = f2h(w * hs);
            float add = ja ? hl[dloc * 32 + c][j] : 0.f;
            hs = fmaf(a64, hs, add);
        }
    }
    // ---- P3: intra Toeplitz (wave 0), in place into ut ----
    if (t < 64) {
        int dloc = t >> 5, c = t & 31;
        int d = d0 + dloc;
        size_t off = (size_t)d * SEQ + c * 64;
        float uu[64];
#pragma unroll
        for (int q = 0; q < 16; ++q) {
            float4 v = *(const float4*)(ut + off + q * 4);
            uu[q * 4 + 0] = v.x; uu[q * 4 + 1] = v.y;
            uu[q * 4 + 2] = v.z; uu[q * 4 + 3] = v.w;
        }
        float e = evec[d];
        float y[64];
#pragma unroll
        for (int tt = 0; tt < 64; ++tt) y[tt] = e * uu[tt];
        const float* kt = &kk[dloc * 64];
#pragma unroll
        for (int dlt = 0; dlt < 64; ++dlt) {
            float k = kt[dlt];
#pragma unroll
            for (int tt = dlt; tt < 64; ++tt)
                y[tt] = fmaf(k, uu[tt - dlt], y[tt]);
        }
#pragma unroll
        for (int q = 0; q < 16; ++q) {
            float4 v = make_float4(y[q * 4 + 0], y[q * 4 + 1], y[q * 4 + 2], y[q * 4 + 3]);
            *(float4*)(ut + off + q * 4) = v;
        }
    }
}

// ---------------------------------------------------------------------------
// inter: out[c*64+t][d] = (E @ G_c)[t][d] + yintra[d][c*64+t]
// Block = (chunk c, 64-wide d tile): M=64, N=64, K=128 fp16, 4 waves.
// ---------------------------------------------------------------------------
__global__ __launch_bounds__(256) void inter(const unsigned short* __restrict__ Eh,
                                             const unsigned short* __restrict__ Gh,
                                             const float* __restrict__ yintra,
                                             float* __restrict__ out) {
    __shared__ float yl[64][68];
    int c = blockIdx.x;
    int d0 = blockIdx.y * 64;
    int t = threadIdx.x;
#pragma unroll
    for (int it = 0; it < 4; ++it) {
        int idx = t + it * 256;
        int row = idx >> 4, col4 = (idx & 15) * 4;
        float4 v = *(const float4*)&yintra[(size_t)(d0 + row) * SEQ + c * 64 + col4];
        yl[col4 + 0][row] = v.x;
        yl[col4 + 1][row] = v.y;
        yl[col4 + 2][row] = v.z;
        yl[col4 + 3][row] = v.w;
    }
    __syncthreads();
    int wave = t >> 6, lane = t & 63;
    int wn = wave * 16;
    int m16 = lane & 15, quad = lane >> 4;
    float4v acc[4];
#pragma unroll
    for (int mt = 0; mt < 4; ++mt) acc[mt] = (float4v){0.f, 0.f, 0.f, 0.f};
#pragma unroll
    for (int ks = 0; ks < 4; ++ks) {
        half8 bh = *(const half8*)(Gh + ((size_t)c * DM + d0 + wn + m16) * KJ + ks * 32 + quad * 8);
#pragma unroll
        for (int mt = 0; mt < 4; ++mt) {
            half8 ah = *(const half8*)(Eh + (mt * 16 + m16) * KJ + ks * 32 + quad * 8);
            acc[mt] = __builtin_amdgcn_mfma_f32_16x16x32_f16(ah, bh, acc[mt], 0, 0, 0);
        }
    }
#pragma unroll
    for (int mt = 0; mt < 4; ++mt) {
        int tt = mt * 16 + quad * 4;
        int dcol = wn + m16;
#pragma unroll
        for (int i = 0; i < 4; ++i) {
            float v = acc[mt][i] + yl[tt + i][dcol];
            out[(size_t)(c * 64 + tt + i) * DM + d0 + dcol] = v;
        }
    }
}

extern "C" void kernel_launch(void* const* d_in, const int* in_sizes, int n_in,
                              void* d_out, int out_size, void* d_ws, size_t ws_size,
                              hipStream_t stream) {
    const float* x  = (const float*)d_in[0];
    const float* Mi = (const float*)d_in[2];
    const float* Mf = (const float*)d_in[3];
    const float* Av = (const float*)d_in[4];
    const float* Bv = (const float*)d_in[5];
    const float* C  = (const float*)d_in[6];
    const float* Dv = (const float*)d_in[7];
    float* out = (float*)d_out;

    float* ut   = (float*)d_ws;                           // 768*2048 f32
    float* WpT  = ut + (size_t)DM * SEQ;                  // 768*100
    float* ev   = WpT + DM * ST;                          // 768
    float* Apow = ev + DM;                                // 65*100
    unsigned short* Mh = (unsigned short*)(Apow + 65 * ST);   // 768*768 fp16
    unsigned short* Xh = Mh + (size_t)DM * DM;            // 2048*768 fp16
    unsigned short* Eh = Xh + (size_t)SEQ * DM;           // 64*128 fp16
    unsigned short* Qh = Eh + 64 * KJ;                    // 112*64 fp16
    unsigned short* Gh = Qh + NJ * 64;                    // 32*768*128 fp16

    prep<<<1213, 256, 0, stream>>>(x, Mi, C, Dv, Mf, Av, Bv, Mh, Xh,
                                   WpT, ev, Apow, Eh, Qh);
    gemm_mfma<<<(DM / 64) * (SEQ / 64), 256, 0, stream>>>(Mh, Xh, ut);
    scanf_k<<<384, 256, 0, stream>>>(ut, Qh, WpT, Apow, Bv, ev, Gh);
    inter<<<dim3(NC, DM / 64), 256, 0, stream>>>(Eh, Gh, ut, out);
}